// Round 1
// baseline (14818.875 us; speedup 1.0000x reference)
//
#include <hip/hip_runtime.h>
#include <hip/hip_bf16.h>
#include <math.h>

// Problem constants
#define V_SZ 32000
#define D_SZ 768
#define H_SZ 12
#define L_SZ 12
#define DF_SZ 3072
#define B_SZ 2
#define S_SZ 1024
#define BS_SZ 16
#define HD_SZ 64
#define MASK_ID 31999
#define NTOK (B_SZ * S_SZ)   // 2048

// ---------------------------------------------------------------------------
// Embedding gather + rotary (applied once to embeddings, per reference)
// ---------------------------------------------------------------------------
__global__ __launch_bounds__(256) void embed_rot_kernel(
    const int* __restrict__ ids, const float* __restrict__ emb,
    float* __restrict__ x)
{
    const int tok = blockIdx.x;          // 0..2047
    const int s = tok & (S_SZ - 1);      // position in sequence
    const int id = ids[tok];
    const float* e = emb + (size_t)id * D_SZ;
    float* xo = x + (size_t)tok * D_SZ;
    const int t = threadIdx.x;

    // rotary pairs p = 0..191 over channels [0, 384)
    if (t < 192) {
        float x0 = e[2 * t], x1 = e[2 * t + 1];
        float freq = powf(10000.f, -((float)(2 * t)) / 384.f);
        float ang = (float)s * freq;
        float sn, cs;
        sincosf(ang, &sn, &cs);
        xo[2 * t]     = x0 * cs - x1 * sn;
        xo[2 * t + 1] = x0 * sn + x1 * cs;
    }
    // pass-through channels [384, 768)
    for (int ch = 384 + t; ch < D_SZ; ch += 256) xo[ch] = e[ch];
}

// ---------------------------------------------------------------------------
// LayerNorm: one block (256 threads) per row of 768
// ---------------------------------------------------------------------------
__global__ __launch_bounds__(256) void ln_kernel(
    const float* __restrict__ x, const float* __restrict__ w,
    const float* __restrict__ b, float* __restrict__ out)
{
    const int row = blockIdx.x;
    const int t = threadIdx.x;
    const float* xr = x + (size_t)row * D_SZ;
    __shared__ float red[256];

    float v0 = xr[t], v1 = xr[t + 256], v2 = xr[t + 512];
    red[t] = v0 + v1 + v2;
    __syncthreads();
    for (int off = 128; off; off >>= 1) {
        if (t < off) red[t] += red[t + off];
        __syncthreads();
    }
    float mean = red[0] * (1.f / 768.f);
    __syncthreads();
    float d0 = v0 - mean, d1 = v1 - mean, d2 = v2 - mean;
    red[t] = d0 * d0 + d1 * d1 + d2 * d2;
    __syncthreads();
    for (int off = 128; off; off >>= 1) {
        if (t < off) red[t] += red[t + off];
        __syncthreads();
    }
    float rstd = rsqrtf(red[0] * (1.f / 768.f) + 1e-5f);
    float* o = out + (size_t)row * D_SZ;
    o[t]       = d0 * rstd * w[t]       + b[t];
    o[t + 256] = d1 * rstd * w[t + 256] + b[t + 256];
    o[t + 512] = d2 * rstd * w[t + 512] + b[t + 512];
}

// ---------------------------------------------------------------------------
// Generic GEMM: C[M,N] = act(A[M,K] @ W[N,K]^T + bias) + Res
// 128x128 tile, BK=16, 256 threads, 8x8 per thread. All dims divide exactly.
// gelu_flag: apply exact GELU (before residual). Res/bias may be null.
// ---------------------------------------------------------------------------
__global__ __launch_bounds__(256) void gemm_kernel(
    const float* __restrict__ A, const float* __restrict__ W,
    const float* __restrict__ bias, const float* __restrict__ Res,
    float* __restrict__ C, int M, int N, int K, int gelu_flag)
{
    __shared__ float As[16][132];   // [k][m], pad 4 keeps float4 alignment
    __shared__ float Bs[16][132];   // [k][n]
    const int tid = threadIdx.x;
    const int tx = tid & 15, ty = tid >> 4;
    const int m0 = blockIdx.y * 128, n0 = blockIdx.x * 128;

    float acc[8][8];
#pragma unroll
    for (int i = 0; i < 8; ++i)
#pragma unroll
        for (int j = 0; j < 8; ++j) acc[i][j] = 0.f;

    for (int k0 = 0; k0 < K; k0 += 16) {
#pragma unroll
        for (int i = 0; i < 2; ++i) {
            int li = tid + i * 256;          // 0..511
            int r = li >> 2;                 // tile row 0..127
            int c4 = (li & 3) << 2;          // k offset {0,4,8,12}
            float4 va = *(const float4*)(A + (size_t)(m0 + r) * K + k0 + c4);
            As[c4 + 0][r] = va.x; As[c4 + 1][r] = va.y;
            As[c4 + 2][r] = va.z; As[c4 + 3][r] = va.w;
            float4 vb = *(const float4*)(W + (size_t)(n0 + r) * K + k0 + c4);
            Bs[c4 + 0][r] = vb.x; Bs[c4 + 1][r] = vb.y;
            Bs[c4 + 2][r] = vb.z; Bs[c4 + 3][r] = vb.w;
        }
        __syncthreads();
#pragma unroll
        for (int kk = 0; kk < 16; ++kk) {
            float a[8], bb[8];
            *(float4*)&a[0]  = *(const float4*)&As[kk][ty * 8];
            *(float4*)&a[4]  = *(const float4*)&As[kk][ty * 8 + 4];
            *(float4*)&bb[0] = *(const float4*)&Bs[kk][tx * 8];
            *(float4*)&bb[4] = *(const float4*)&Bs[kk][tx * 8 + 4];
#pragma unroll
            for (int i = 0; i < 8; ++i)
#pragma unroll
                for (int j = 0; j < 8; ++j)
                    acc[i][j] = fmaf(a[i], bb[j], acc[i][j]);
        }
        __syncthreads();
    }

#pragma unroll
    for (int i = 0; i < 8; ++i) {
        int row = m0 + ty * 8 + i;
        size_t base = (size_t)row * N + n0 + tx * 8;
#pragma unroll
        for (int j = 0; j < 8; ++j) {
            float v = acc[i][j];
            if (bias) v += bias[n0 + tx * 8 + j];
            if (gelu_flag) v = 0.5f * v * (1.f + erff(v * 0.70710678118654752f));
            if (Res) v += Res[base + j];
            C[base + j] = v;
        }
    }
}

// ---------------------------------------------------------------------------
// Attention: one block per (b, h, q-block of 16 rows). Block-causal mask
// => all 16 q rows share kmax = (qb+1)*16. Online softmax over k-chunks of 64.
// 4 waves; wave w owns q rows w*4..w*4+3. Lane j computes score vs k-pos j;
// lane d accumulates output channel d.
// ---------------------------------------------------------------------------
__global__ __launch_bounds__(256) void attn_kernel(
    const float* __restrict__ qkv, float* __restrict__ out)
{
    const int bid = blockIdx.x;
    const int qb = bid & 63;               // 64 q-blocks
    const int h  = (bid >> 6) % H_SZ;
    const int b  = bid / (64 * H_SZ);
    const int tid = threadIdx.x;
    const int wave = tid >> 6, lane = tid & 63;

    __shared__ float Kl[64][65];
    __shared__ float Vl[64][65];
    __shared__ float Ql[16][64];
    __shared__ float Pl[4][4][64];         // [wave][row][k-pos]

    // stage Q (16 rows x 64 ch): 256 float4s
    {
        int r = tid >> 4, c4 = (tid & 15) << 2;
        const float* src = qkv + ((size_t)(b * S_SZ + qb * 16 + r)) * (3 * D_SZ)
                               + h * HD_SZ + c4;
        float4 v = *(const float4*)src;
        Ql[r][c4 + 0] = v.x; Ql[r][c4 + 1] = v.y;
        Ql[r][c4 + 2] = v.z; Ql[r][c4 + 3] = v.w;
    }

    const int kmax = (qb + 1) * BS_SZ;
    const int nchunk = (kmax + 63) >> 6;

    float m[4], l[4], o[4], corr[4];
#pragma unroll
    for (int r = 0; r < 4; ++r) { m[r] = -1e30f; l[r] = 0.f; o[r] = 0.f; }

    for (int c = 0; c < nchunk; ++c) {
        __syncthreads();   // prior o-phase / Q staging done before overwrite
        // stage K,V chunk (64 rows x 64 ch each)
#pragma unroll
        for (int i = 0; i < 4; ++i) {
            int li = tid + i * 256;            // 0..1023
            int r = li >> 4, c4 = (li & 15) << 2;
            const float* base = qkv + ((size_t)(b * S_SZ + c * 64 + r)) * (3 * D_SZ)
                                    + h * HD_SZ + c4;
            float4 kv = *(const float4*)(base + D_SZ);
            float4 vv = *(const float4*)(base + 2 * D_SZ);
            Kl[r][c4 + 0] = kv.x; Kl[r][c4 + 1] = kv.y;
            Kl[r][c4 + 2] = kv.z; Kl[r][c4 + 3] = kv.w;
            Vl[r][c4 + 0] = vv.x; Vl[r][c4 + 1] = vv.y;
            Vl[r][c4 + 2] = vv.z; Vl[r][c4 + 3] = vv.w;
        }
        __syncthreads();

        // score phase: lane j handles k position c*64 + j
        const int jg = c * 64 + lane;
        const float maskadd = (jg >= kmax) ? -1e9f : 0.f;
#pragma unroll
        for (int r = 0; r < 4; ++r) {
            const int row = wave * 4 + r;
            float s = 0.f;
#pragma unroll
            for (int d = 0; d < 64; ++d) s = fmaf(Ql[row][d], Kl[lane][d], s);
            s = s * 0.125f + maskadd;
            float cm = s;
#pragma unroll
            for (int off = 32; off; off >>= 1) cm = fmaxf(cm, __shfl_xor(cm, off));
            float mn = fmaxf(m[r], cm);
            corr[r] = expf(m[r] - mn);
            float p = expf(s - mn);
            float ps = p;
#pragma unroll
            for (int off = 32; off; off >>= 1) ps += __shfl_xor(ps, off);
            l[r] = l[r] * corr[r] + ps;
            m[r] = mn;
            Pl[wave][r][lane] = p;
        }
        __syncthreads();

        // o phase: lane d = lane accumulates channel d
#pragma unroll
        for (int r = 0; r < 4; ++r) {
            float acc = 0.f;
#pragma unroll
            for (int j = 0; j < 64; ++j)
                acc = fmaf(Pl[wave][r][j], Vl[j][lane], acc);
            o[r] = o[r] * corr[r] + acc;
        }
    }

    // store: out[b, qb*16 + wave*4 + r, h*64 + lane] = o/l
#pragma unroll
    for (int r = 0; r < 4; ++r) {
        const int row = b * S_SZ + qb * 16 + wave * 4 + r;
        out[(size_t)row * D_SZ + h * HD_SZ + lane] = o[r] / l[r];
    }
}

// ---------------------------------------------------------------------------
// Per-row CE: max + sumexp over 32000 logits, gather target
// ---------------------------------------------------------------------------
__global__ __launch_bounds__(256) void ce_kernel(
    const float* __restrict__ logits, const int* __restrict__ tgt,
    const int* __restrict__ inp, const float* __restrict__ noise,
    float* __restrict__ ce_row, float* __restrict__ msk_row)
{
    const int row = blockIdx.x;
    const int t = threadIdx.x;
    const float* lr = logits + (size_t)row * V_SZ;
    __shared__ float red[256];

    float mx = -1e30f;
    for (int i = t; i < V_SZ; i += 256) mx = fmaxf(mx, lr[i]);
    red[t] = mx;
    __syncthreads();
    for (int off = 128; off; off >>= 1) {
        if (t < off) red[t] = fmaxf(red[t], red[t + off]);
        __syncthreads();
    }
    float M = red[0];
    __syncthreads();
    float s = 0.f;
    for (int i = t; i < V_SZ; i += 256) s += expf(lr[i] - M);
    red[t] = s;
    __syncthreads();
    for (int off = 128; off; off >>= 1) {
        if (t < off) red[t] += red[t + off];
        __syncthreads();
    }
    if (t == 0) {
        int tg = tgt[row];
        float ce = -(lr[tg] - M - logf(red[0]));
        int ism = (inp[row] == MASK_ID) ? 1 : 0;
        int b = row / S_SZ;
        ce_row[row] = ism ? (ce / noise[b]) : 0.f;
        msk_row[row] = ism ? 1.f : 0.f;
    }
}

__global__ __launch_bounds__(256) void loss_reduce_kernel(
    const float* __restrict__ ce_row, const float* __restrict__ msk_row,
    float* __restrict__ out0)
{
    const int t = threadIdx.x;
    __shared__ float r1[256], r2[256];
    float s = 0.f, c = 0.f;
    for (int i = t; i < NTOK; i += 256) { s += ce_row[i]; c += msk_row[i]; }
    r1[t] = s; r2[t] = c;
    __syncthreads();
    for (int off = 128; off; off >>= 1) {
        if (t < off) { r1[t] += r1[t + off]; r2[t] += r2[t + off]; }
        __syncthreads();
    }
    if (t == 0) out0[0] = r1[0] / (r2[0] + 1e-8f);
}

// ---------------------------------------------------------------------------
// Host launch
// ---------------------------------------------------------------------------
extern "C" void kernel_launch(void* const* d_in, const int* in_sizes, int n_in,
                              void* d_out, int out_size, void* d_ws, size_t ws_size,
                              hipStream_t stream)
{
    const int*   input_ids  = (const int*)d_in[0];
    const int*   target_ids = (const int*)d_in[1];
    const float* noise      = (const float*)d_in[2];
    const float* emb        = (const float*)d_in[3];
    const float* in_w       = (const float*)d_in[4];
    const float* in_b       = (const float*)d_in[5];
    const float* aow        = (const float*)d_in[6];
    const float* aob        = (const float*)d_in[7];
    const float* ln1w       = (const float*)d_in[8];
    const float* ln1b       = (const float*)d_in[9];
    const float* ln2w       = (const float*)d_in[10];
    const float* ln2b       = (const float*)d_in[11];
    const float* w1         = (const float*)d_in[12];
    const float* b1         = (const float*)d_in[13];
    const float* w2         = (const float*)d_in[14];
    const float* b2         = (const float*)d_in[15];
    const float* projw      = (const float*)d_in[16];
    const float* projb      = (const float*)d_in[17];

    float* out    = (float*)d_out;
    float* logits = out + 1;                       // [2048][32000]

    // Large per-layer scratch lives in the tail of d_out (dead before the
    // final logits GEMM overwrites the whole logits region).
    // Layout (element offsets from `out`, all 16B-aligned, end == 65,536,000):
    float* mid  = out + 51380224;   // [2048][3072]  6,291,456
    float* qkv  = out + 57671680;   // [2048][2304]  4,718,592
    float* hbuf = out + 62390272;   // [2048][768]   1,572,864
    float* ao   = out + 63963136;   // [2048][768]   1,572,864

    // x must survive the logits GEMM -> keep in d_ws (~6.1 MB used)
    float* x       = (float*)d_ws;                 // [2048][768]
    float* ce_row  = x + (size_t)NTOK * D_SZ;      // [2048]
    float* msk_row = ce_row + NTOK;                // [2048]

    embed_rot_kernel<<<NTOK, 256, 0, stream>>>(input_ids, emb, x);

    for (int l = 0; l < L_SZ; ++l) {
        ln_kernel<<<NTOK, 256, 0, stream>>>(x, ln1w + l * D_SZ, ln1b + l * D_SZ, hbuf);
        gemm_kernel<<<dim3(18, 16), 256, 0, stream>>>(
            hbuf, in_w + (size_t)l * 3 * D_SZ * D_SZ, in_b + (size_t)l * 3 * D_SZ,
            nullptr, qkv, NTOK, 3 * D_SZ, D_SZ, 0);
        attn_kernel<<<B_SZ * H_SZ * 64, 256, 0, stream>>>(qkv, ao);
        gemm_kernel<<<dim3(6, 16), 256, 0, stream>>>(
            ao, aow + (size_t)l * D_SZ * D_SZ, aob + (size_t)l * D_SZ,
            x, x, NTOK, D_SZ, D_SZ, 0);
        ln_kernel<<<NTOK, 256, 0, stream>>>(x, ln2w + l * D_SZ, ln2b + l * D_SZ, hbuf);
        gemm_kernel<<<dim3(24, 16), 256, 0, stream>>>(
            hbuf, w1 + (size_t)l * DF_SZ * D_SZ, b1 + (size_t)l * DF_SZ,
            nullptr, mid, NTOK, DF_SZ, D_SZ, 1);
        gemm_kernel<<<dim3(6, 16), 256, 0, stream>>>(
            mid, w2 + (size_t)l * D_SZ * DF_SZ, b2 + (size_t)l * D_SZ,
            x, x, NTOK, D_SZ, DF_SZ, 0);
    }

    gemm_kernel<<<dim3(250, 16), 256, 0, stream>>>(
        x, projw, projb, nullptr, logits, NTOK, V_SZ, D_SZ, 0);

    ce_kernel<<<NTOK, 256, 0, stream>>>(logits, target_ids, input_ids, noise,
                                        ce_row, msk_row);
    loss_reduce_kernel<<<1, 256, 0, stream>>>(ce_row, msk_row, out);
}

// Round 2
// 6263.599 us; speedup vs baseline: 2.3659x; 2.3659x over previous
//
#include <hip/hip_runtime.h>
#include <hip/hip_bf16.h>
#include <math.h>

// Problem constants
#define V_SZ 32000
#define D_SZ 768
#define H_SZ 12
#define L_SZ 12
#define DF_SZ 3072
#define B_SZ 2
#define S_SZ 1024
#define BS_SZ 16
#define HD_SZ 64
#define MASK_ID 31999
#define NTOK (B_SZ * S_SZ)   // 2048

typedef __attribute__((ext_vector_type(8))) short bf16x8;
typedef __attribute__((ext_vector_type(4))) float f32x4;

union B8 { bf16x8 v; __hip_bfloat162 h[4]; };

// ---------------------------------------------------------------------------
// Embedding gather + rotary
// ---------------------------------------------------------------------------
__global__ __launch_bounds__(256) void embed_rot_kernel(
    const int* __restrict__ ids, const float* __restrict__ emb,
    float* __restrict__ x)
{
    const int tok = blockIdx.x;
    const int s = tok & (S_SZ - 1);
    const int id = ids[tok];
    const float* e = emb + (size_t)id * D_SZ;
    float* xo = x + (size_t)tok * D_SZ;
    const int t = threadIdx.x;

    if (t < 192) {
        float x0 = e[2 * t], x1 = e[2 * t + 1];
        float freq = powf(10000.f, -((float)(2 * t)) / 384.f);
        float ang = (float)s * freq;
        float sn, cs;
        sincosf(ang, &sn, &cs);
        xo[2 * t]     = x0 * cs - x1 * sn;
        xo[2 * t + 1] = x0 * sn + x1 * cs;
    }
    for (int ch = 384 + t; ch < D_SZ; ch += 256) xo[ch] = e[ch];
}

// ---------------------------------------------------------------------------
// LayerNorm: one block (256 threads) per row of 768
// ---------------------------------------------------------------------------
__global__ __launch_bounds__(256) void ln_kernel(
    const float* __restrict__ x, const float* __restrict__ w,
    const float* __restrict__ b, float* __restrict__ out)
{
    const int row = blockIdx.x;
    const int t = threadIdx.x;
    const float* xr = x + (size_t)row * D_SZ;
    __shared__ float red[256];

    float v0 = xr[t], v1 = xr[t + 256], v2 = xr[t + 512];
    red[t] = v0 + v1 + v2;
    __syncthreads();
    for (int off = 128; off; off >>= 1) {
        if (t < off) red[t] += red[t + off];
        __syncthreads();
    }
    float mean = red[0] * (1.f / 768.f);
    __syncthreads();
    float d0 = v0 - mean, d1 = v1 - mean, d2 = v2 - mean;
    red[t] = d0 * d0 + d1 * d1 + d2 * d2;
    __syncthreads();
    for (int off = 128; off; off >>= 1) {
        if (t < off) red[t] += red[t + off];
        __syncthreads();
    }
    float rstd = rsqrtf(red[0] * (1.f / 768.f) + 1e-5f);
    float* o = out + (size_t)row * D_SZ;
    o[t]       = d0 * rstd * w[t]       + b[t];
    o[t + 256] = d1 * rstd * w[t + 256] + b[t + 256];
    o[t + 512] = d2 * rstd * w[t + 512] + b[t + 512];
}

// ---------------------------------------------------------------------------
// MFMA bf16 GEMM: C[M,N] = act(A[M,K] @ W[N,K]^T + bias) [+ Res]
// A,W are f32 in HBM; converted to bf16 during LDS staging (reg-staged).
// BMxBN tile, BK=32, 256 threads = 4 waves (2x2), wave tile (BM/2)x(BN/2),
// mfma_f32_16x16x32_bf16 fragments. LDS rows padded +8 bf16 (stride 80B)
// to spread the stride-64B bank pattern.
// Requires: M%BM==0, N%BN==0, K%32==0 (true for all 5 shapes).
// ---------------------------------------------------------------------------
template<int BM, int BN>
__global__ __launch_bounds__(256) void mfma_gemm(
    const float* __restrict__ A, const float* __restrict__ W,
    const float* __restrict__ bias, const float* __restrict__ Res,
    float* __restrict__ C, int M, int N, int K, int gelu_flag)
{
    constexpr int LDST = 40;            // bf16 per LDS row (32 + 8 pad)
    constexpr int MR = BM / 32;         // 16x16 frags per wave, M dir
    constexpr int NR = BN / 32;         // 16x16 frags per wave, N dir
    constexpr int ACH = BM * 4 / 256;   // A 8-elem chunks per thread
    constexpr int BCH = BN * 4 / 256;

    __shared__ __align__(16) unsigned short As[2][BM * LDST];
    __shared__ __align__(16) unsigned short Bs[2][BN * LDST];

    const int tid = threadIdx.x;
    const int lane = tid & 63;
    const int wave = tid >> 6;
    const int wm = wave >> 1, wn = wave & 1;
    const int wrow0 = wm * (BM / 2);
    const int wcol0 = wn * (BN / 2);
    const int kgrp = lane >> 4;         // 0..3
    const int rc = lane & 15;

    const int m0 = blockIdx.y * BM;
    const int n0 = blockIdx.x * BN;

    f32x4 acc[MR][NR];
#pragma unroll
    for (int i = 0; i < MR; ++i)
#pragma unroll
        for (int j = 0; j < NR; ++j) acc[i][j] = (f32x4){0.f, 0.f, 0.f, 0.f};

    float areg[ACH][8];
    float breg[BCH][8];

    // ---- staging helpers (manually inlined via lambdas) ----
    auto stage_load = [&](int k0) {
#pragma unroll
        for (int i = 0; i < ACH; ++i) {
            int c = tid + i * 256;
            int row = c >> 2, ks = c & 3;
            const float* p = A + (size_t)(m0 + row) * K + k0 + ks * 8;
            float4 v0 = *(const float4*)p;
            float4 v1 = *(const float4*)(p + 4);
            areg[i][0] = v0.x; areg[i][1] = v0.y; areg[i][2] = v0.z; areg[i][3] = v0.w;
            areg[i][4] = v1.x; areg[i][5] = v1.y; areg[i][6] = v1.z; areg[i][7] = v1.w;
        }
#pragma unroll
        for (int i = 0; i < BCH; ++i) {
            int c = tid + i * 256;
            int row = c >> 2, ks = c & 3;
            const float* p = W + (size_t)(n0 + row) * K + k0 + ks * 8;
            float4 v0 = *(const float4*)p;
            float4 v1 = *(const float4*)(p + 4);
            breg[i][0] = v0.x; breg[i][1] = v0.y; breg[i][2] = v0.z; breg[i][3] = v0.w;
            breg[i][4] = v1.x; breg[i][5] = v1.y; breg[i][6] = v1.z; breg[i][7] = v1.w;
        }
    };
    auto stage_write = [&](int buf) {
#pragma unroll
        for (int i = 0; i < ACH; ++i) {
            int c = tid + i * 256;
            int row = c >> 2, ks = c & 3;
            B8 r;
            r.h[0] = __float22bfloat162_rn(float2{areg[i][0], areg[i][1]});
            r.h[1] = __float22bfloat162_rn(float2{areg[i][2], areg[i][3]});
            r.h[2] = __float22bfloat162_rn(float2{areg[i][4], areg[i][5]});
            r.h[3] = __float22bfloat162_rn(float2{areg[i][6], areg[i][7]});
            *(bf16x8*)&As[buf][row * LDST + ks * 8] = r.v;
        }
#pragma unroll
        for (int i = 0; i < BCH; ++i) {
            int c = tid + i * 256;
            int row = c >> 2, ks = c & 3;
            B8 r;
            r.h[0] = __float22bfloat162_rn(float2{breg[i][0], breg[i][1]});
            r.h[1] = __float22bfloat162_rn(float2{breg[i][2], breg[i][3]});
            r.h[2] = __float22bfloat162_rn(float2{breg[i][4], breg[i][5]});
            r.h[3] = __float22bfloat162_rn(float2{breg[i][6], breg[i][7]});
            *(bf16x8*)&Bs[buf][row * LDST + ks * 8] = r.v;
        }
    };

    // prologue
    stage_load(0);
    stage_write(0);
    __syncthreads();

    const int nk = K >> 5;
    int cur = 0;
    for (int s = 0; s < nk; ++s) {
        const bool more = (s + 1 < nk);
        if (more) stage_load((s + 1) << 5);   // issue next-tile global loads

        bf16x8 af[MR], bf[NR];
#pragma unroll
        for (int mi = 0; mi < MR; ++mi)
            af[mi] = *(const bf16x8*)&As[cur][(wrow0 + mi * 16 + rc) * LDST + kgrp * 8];
#pragma unroll
        for (int ni = 0; ni < NR; ++ni)
            bf[ni] = *(const bf16x8*)&Bs[cur][(wcol0 + ni * 16 + rc) * LDST + kgrp * 8];
#pragma unroll
        for (int mi = 0; mi < MR; ++mi)
#pragma unroll
            for (int ni = 0; ni < NR; ++ni)
                acc[mi][ni] = __builtin_amdgcn_mfma_f32_16x16x32_bf16(
                    af[mi], bf[ni], acc[mi][ni], 0, 0, 0);

        if (more) stage_write(cur ^ 1);
        __syncthreads();
        cur ^= 1;
    }

    // epilogue: D frag elem i -> row = kgrp*4 + i, col = rc (within 16x16)
#pragma unroll
    for (int mi = 0; mi < MR; ++mi) {
#pragma unroll
        for (int ni = 0; ni < NR; ++ni) {
            const int col = n0 + wcol0 + ni * 16 + rc;
            const int rbase = m0 + wrow0 + mi * 16 + kgrp * 4;
            float bv = bias ? bias[col] : 0.f;
#pragma unroll
            for (int i = 0; i < 4; ++i) {
                float v = acc[mi][ni][i] + bv;
                if (gelu_flag) v = 0.5f * v * (1.f + erff(v * 0.70710678118654752f));
                size_t idx = (size_t)(rbase + i) * N + col;
                if (Res) v += Res[idx];
                C[idx] = v;
            }
        }
    }
}

// ---------------------------------------------------------------------------
// Attention (unchanged): one block per (b, h, 16-row q-block), f32.
// ---------------------------------------------------------------------------
__global__ __launch_bounds__(256) void attn_kernel(
    const float* __restrict__ qkv, float* __restrict__ out)
{
    const int bid = blockIdx.x;
    const int qb = bid & 63;
    const int h  = (bid >> 6) % H_SZ;
    const int b  = bid / (64 * H_SZ);
    const int tid = threadIdx.x;
    const int wave = tid >> 6, lane = tid & 63;

    __shared__ float Kl[64][65];
    __shared__ float Vl[64][65];
    __shared__ float Ql[16][64];
    __shared__ float Pl[4][4][64];

    {
        int r = tid >> 4, c4 = (tid & 15) << 2;
        const float* src = qkv + ((size_t)(b * S_SZ + qb * 16 + r)) * (3 * D_SZ)
                               + h * HD_SZ + c4;
        float4 v = *(const float4*)src;
        Ql[r][c4 + 0] = v.x; Ql[r][c4 + 1] = v.y;
        Ql[r][c4 + 2] = v.z; Ql[r][c4 + 3] = v.w;
    }

    const int kmax = (qb + 1) * BS_SZ;
    const int nchunk = (kmax + 63) >> 6;

    float m[4], l[4], o[4], corr[4];
#pragma unroll
    for (int r = 0; r < 4; ++r) { m[r] = -1e30f; l[r] = 0.f; o[r] = 0.f; }

    for (int c = 0; c < nchunk; ++c) {
        __syncthreads();
#pragma unroll
        for (int i = 0; i < 4; ++i) {
            int li = tid + i * 256;
            int r = li >> 4, c4 = (li & 15) << 2;
            const float* base = qkv + ((size_t)(b * S_SZ + c * 64 + r)) * (3 * D_SZ)
                                    + h * HD_SZ + c4;
            float4 kv = *(const float4*)(base + D_SZ);
            float4 vv = *(const float4*)(base + 2 * D_SZ);
            Kl[r][c4 + 0] = kv.x; Kl[r][c4 + 1] = kv.y;
            Kl[r][c4 + 2] = kv.z; Kl[r][c4 + 3] = kv.w;
            Vl[r][c4 + 0] = vv.x; Vl[r][c4 + 1] = vv.y;
            Vl[r][c4 + 2] = vv.z; Vl[r][c4 + 3] = vv.w;
        }
        __syncthreads();

        const int jg = c * 64 + lane;
        const float maskadd = (jg >= kmax) ? -1e9f : 0.f;
#pragma unroll
        for (int r = 0; r < 4; ++r) {
            const int row = wave * 4 + r;
            float s = 0.f;
#pragma unroll
            for (int d = 0; d < 64; ++d) s = fmaf(Ql[row][d], Kl[lane][d], s);
            s = s * 0.125f + maskadd;
            float cm = s;
#pragma unroll
            for (int off = 32; off; off >>= 1) cm = fmaxf(cm, __shfl_xor(cm, off));
            float mn = fmaxf(m[r], cm);
            corr[r] = expf(m[r] - mn);
            float p = expf(s - mn);
            float ps = p;
#pragma unroll
            for (int off = 32; off; off >>= 1) ps += __shfl_xor(ps, off);
            l[r] = l[r] * corr[r] + ps;
            m[r] = mn;
            Pl[wave][r][lane] = p;
        }
        __syncthreads();

#pragma unroll
        for (int r = 0; r < 4; ++r) {
            float acc = 0.f;
#pragma unroll
            for (int j = 0; j < 64; ++j)
                acc = fmaf(Pl[wave][r][j], Vl[j][lane], acc);
            o[r] = o[r] * corr[r] + acc;
        }
    }

#pragma unroll
    for (int r = 0; r < 4; ++r) {
        const int row = b * S_SZ + qb * 16 + wave * 4 + r;
        out[(size_t)row * D_SZ + h * HD_SZ + lane] = o[r] / l[r];
    }
}

// ---------------------------------------------------------------------------
// Per-row CE + final reduce (unchanged)
// ---------------------------------------------------------------------------
__global__ __launch_bounds__(256) void ce_kernel(
    const float* __restrict__ logits, const int* __restrict__ tgt,
    const int* __restrict__ inp, const float* __restrict__ noise,
    float* __restrict__ ce_row, float* __restrict__ msk_row)
{
    const int row = blockIdx.x;
    const int t = threadIdx.x;
    const float* lr = logits + (size_t)row * V_SZ;
    __shared__ float red[256];

    float mx = -1e30f;
    for (int i = t; i < V_SZ; i += 256) mx = fmaxf(mx, lr[i]);
    red[t] = mx;
    __syncthreads();
    for (int off = 128; off; off >>= 1) {
        if (t < off) red[t] = fmaxf(red[t], red[t + off]);
        __syncthreads();
    }
    float M = red[0];
    __syncthreads();
    float s = 0.f;
    for (int i = t; i < V_SZ; i += 256) s += expf(lr[i] - M);
    red[t] = s;
    __syncthreads();
    for (int off = 128; off; off >>= 1) {
        if (t < off) red[t] += red[t + off];
        __syncthreads();
    }
    if (t == 0) {
        int tg = tgt[row];
        float ce = -(lr[tg] - M - logf(red[0]));
        int ism = (inp[row] == MASK_ID) ? 1 : 0;
        int b = row / S_SZ;
        ce_row[row] = ism ? (ce / noise[b]) : 0.f;
        msk_row[row] = ism ? 1.f : 0.f;
    }
}

__global__ __launch_bounds__(256) void loss_reduce_kernel(
    const float* __restrict__ ce_row, const float* __restrict__ msk_row,
    float* __restrict__ out0)
{
    const int t = threadIdx.x;
    __shared__ float r1[256], r2[256];
    float s = 0.f, c = 0.f;
    for (int i = t; i < NTOK; i += 256) { s += ce_row[i]; c += msk_row[i]; }
    r1[t] = s; r2[t] = c;
    __syncthreads();
    for (int off = 128; off; off >>= 1) {
        if (t < off) { r1[t] += r1[t + off]; r2[t] += r2[t + off]; }
        __syncthreads();
    }
    if (t == 0) out0[0] = r1[0] / (r2[0] + 1e-8f);
}

// ---------------------------------------------------------------------------
// Host launch
// ---------------------------------------------------------------------------
extern "C" void kernel_launch(void* const* d_in, const int* in_sizes, int n_in,
                              void* d_out, int out_size, void* d_ws, size_t ws_size,
                              hipStream_t stream)
{
    const int*   input_ids  = (const int*)d_in[0];
    const int*   target_ids = (const int*)d_in[1];
    const float* noise      = (const float*)d_in[2];
    const float* emb        = (const float*)d_in[3];
    const float* in_w       = (const float*)d_in[4];
    const float* in_b       = (const float*)d_in[5];
    const float* aow        = (const float*)d_in[6];
    const float* aob        = (const float*)d_in[7];
    const float* ln1w       = (const float*)d_in[8];
    const float* ln1b       = (const float*)d_in[9];
    const float* ln2w       = (const float*)d_in[10];
    const float* ln2b       = (const float*)d_in[11];
    const float* w1         = (const float*)d_in[12];
    const float* b1         = (const float*)d_in[13];
    const float* w2         = (const float*)d_in[14];
    const float* b2         = (const float*)d_in[15];
    const float* projw      = (const float*)d_in[16];
    const float* projb      = (const float*)d_in[17];

    float* out    = (float*)d_out;
    float* logits = out + 1;                       // [2048][32000]

    // Large per-layer scratch in the tail of d_out (dead before logits GEMM)
    float* mid  = out + 51380224;   // [2048][3072]
    float* qkv  = out + 57671680;   // [2048][2304]
    float* hbuf = out + 62390272;   // [2048][768]
    float* ao   = out + 63963136;   // [2048][768]

    float* x       = (float*)d_ws;                 // [2048][768], survives logits
    float* ce_row  = x + (size_t)NTOK * D_SZ;
    float* msk_row = ce_row + NTOK;

    embed_rot_kernel<<<NTOK, 256, 0, stream>>>(input_ids, emb, x);

    for (int l = 0; l < L_SZ; ++l) {
        ln_kernel<<<NTOK, 256, 0, stream>>>(x, ln1w + l * D_SZ, ln1b + l * D_SZ, hbuf);
        mfma_gemm<128, 128><<<dim3(18, 16), 256, 0, stream>>>(
            hbuf, in_w + (size_t)l * 3 * D_SZ * D_SZ, in_b + (size_t)l * 3 * D_SZ,
            nullptr, qkv, NTOK, 3 * D_SZ, D_SZ, 0);
        attn_kernel<<<B_SZ * H_SZ * 64, 256, 0, stream>>>(qkv, ao);
        mfma_gemm<64, 128><<<dim3(6, 32), 256, 0, stream>>>(
            ao, aow + (size_t)l * D_SZ * D_SZ, aob + (size_t)l * D_SZ,
            x, x, NTOK, D_SZ, D_SZ, 0);
        ln_kernel<<<NTOK, 256, 0, stream>>>(x, ln2w + l * D_SZ, ln2b + l * D_SZ, hbuf);
        mfma_gemm<128, 128><<<dim3(24, 16), 256, 0, stream>>>(
            hbuf, w1 + (size_t)l * DF_SZ * D_SZ, b1 + (size_t)l * DF_SZ,
            nullptr, mid, NTOK, DF_SZ, D_SZ, 1);
        mfma_gemm<64, 128><<<dim3(6, 32), 256, 0, stream>>>(
            mid, w2 + (size_t)l * D_SZ * DF_SZ, b2 + (size_t)l * D_SZ,
            x, x, NTOK, D_SZ, DF_SZ, 0);
    }

    mfma_gemm<128, 128><<<dim3(250, 16), 256, 0, stream>>>(
        x, projw, projb, nullptr, logits, NTOK, V_SZ, D_SZ, 0);

    ce_kernel<<<NTOK, 256, 0, stream>>>(logits, target_ids, input_ids, noise,
                                        ce_row, msk_row);
    loss_reduce_kernel<<<1, 256, 0, stream>>>(ce_row, msk_row, out);
}

// Round 3
// 3093.150 us; speedup vs baseline: 4.7909x; 2.0250x over previous
//
#include <hip/hip_runtime.h>
#include <hip/hip_bf16.h>
#include <math.h>

// Problem constants
#define V_SZ 32000
#define D_SZ 768
#define H_SZ 12
#define L_SZ 12
#define DF_SZ 3072
#define B_SZ 2
#define S_SZ 1024
#define BS_SZ 16
#define HD_SZ 64
#define MASK_ID 31999
#define NTOK (B_SZ * S_SZ)   // 2048

typedef __attribute__((ext_vector_type(8))) short bf16x8;
typedef __attribute__((ext_vector_type(4))) short bf16x4;
typedef __attribute__((ext_vector_type(4))) float f32x4;

union B8 { bf16x8 v; __hip_bfloat162 h[4]; };
union B4 { bf16x4 v; __hip_bfloat162 h[2]; };

__device__ inline unsigned short f2bf(float x) {
    __hip_bfloat16 b = __float2bfloat16(x);
    union { __hip_bfloat16 b; unsigned short u; } c; c.b = b;
    return c.u;
}

// ---------------------------------------------------------------------------
// Embedding gather + rotary
// ---------------------------------------------------------------------------
__global__ __launch_bounds__(256) void embed_rot_kernel(
    const int* __restrict__ ids, const float* __restrict__ emb,
    float* __restrict__ x)
{
    const int tok = blockIdx.x;
    const int s = tok & (S_SZ - 1);
    const int id = ids[tok];
    const float* e = emb + (size_t)id * D_SZ;
    float* xo = x + (size_t)tok * D_SZ;
    const int t = threadIdx.x;

    if (t < 192) {
        float x0 = e[2 * t], x1 = e[2 * t + 1];
        float freq = powf(10000.f, -((float)(2 * t)) / 384.f);
        float ang = (float)s * freq;
        float sn, cs;
        sincosf(ang, &sn, &cs);
        xo[2 * t]     = x0 * cs - x1 * sn;
        xo[2 * t + 1] = x0 * sn + x1 * cs;
    }
    for (int ch = 384 + t; ch < D_SZ; ch += 256) xo[ch] = e[ch];
}

// ---------------------------------------------------------------------------
// LayerNorm: one block (256 threads) per row of 768
// ---------------------------------------------------------------------------
__global__ __launch_bounds__(256) void ln_kernel(
    const float* __restrict__ x, const float* __restrict__ w,
    const float* __restrict__ b, float* __restrict__ out)
{
    const int row = blockIdx.x;
    const int t = threadIdx.x;
    const float* xr = x + (size_t)row * D_SZ;
    __shared__ float red[256];

    float v0 = xr[t], v1 = xr[t + 256], v2 = xr[t + 512];
    red[t] = v0 + v1 + v2;
    __syncthreads();
    for (int off = 128; off; off >>= 1) {
        if (t < off) red[t] += red[t + off];
        __syncthreads();
    }
    float mean = red[0] * (1.f / 768.f);
    __syncthreads();
    float d0 = v0 - mean, d1 = v1 - mean, d2 = v2 - mean;
    red[t] = d0 * d0 + d1 * d1 + d2 * d2;
    __syncthreads();
    for (int off = 128; off; off >>= 1) {
        if (t < off) red[t] += red[t + off];
        __syncthreads();
    }
    float rstd = rsqrtf(red[0] * (1.f / 768.f) + 1e-5f);
    float* o = out + (size_t)row * D_SZ;
    o[t]       = d0 * rstd * w[t]       + b[t];
    o[t + 256] = d1 * rstd * w[t + 256] + b[t + 256];
    o[t + 512] = d2 * rstd * w[t + 512] + b[t + 512];
}

// ---------------------------------------------------------------------------
// MFMA bf16 GEMM (unchanged from round 2)
// ---------------------------------------------------------------------------
template<int BM, int BN>
__global__ __launch_bounds__(256) void mfma_gemm(
    const float* __restrict__ A, const float* __restrict__ W,
    const float* __restrict__ bias, const float* __restrict__ Res,
    float* __restrict__ C, int M, int N, int K, int gelu_flag)
{
    constexpr int LDST = 40;
    constexpr int MR = BM / 32;
    constexpr int NR = BN / 32;
    constexpr int ACH = BM * 4 / 256;
    constexpr int BCH = BN * 4 / 256;

    __shared__ __align__(16) unsigned short As[2][BM * LDST];
    __shared__ __align__(16) unsigned short Bs[2][BN * LDST];

    const int tid = threadIdx.x;
    const int lane = tid & 63;
    const int wave = tid >> 6;
    const int wm = wave >> 1, wn = wave & 1;
    const int wrow0 = wm * (BM / 2);
    const int wcol0 = wn * (BN / 2);
    const int kgrp = lane >> 4;
    const int rc = lane & 15;

    const int m0 = blockIdx.y * BM;
    const int n0 = blockIdx.x * BN;

    f32x4 acc[MR][NR];
#pragma unroll
    for (int i = 0; i < MR; ++i)
#pragma unroll
        for (int j = 0; j < NR; ++j) acc[i][j] = (f32x4){0.f, 0.f, 0.f, 0.f};

    float areg[ACH][8];
    float breg[BCH][8];

    auto stage_load = [&](int k0) {
#pragma unroll
        for (int i = 0; i < ACH; ++i) {
            int c = tid + i * 256;
            int row = c >> 2, ks = c & 3;
            const float* p = A + (size_t)(m0 + row) * K + k0 + ks * 8;
            float4 v0 = *(const float4*)p;
            float4 v1 = *(const float4*)(p + 4);
            areg[i][0] = v0.x; areg[i][1] = v0.y; areg[i][2] = v0.z; areg[i][3] = v0.w;
            areg[i][4] = v1.x; areg[i][5] = v1.y; areg[i][6] = v1.z; areg[i][7] = v1.w;
        }
#pragma unroll
        for (int i = 0; i < BCH; ++i) {
            int c = tid + i * 256;
            int row = c >> 2, ks = c & 3;
            const float* p = W + (size_t)(n0 + row) * K + k0 + ks * 8;
            float4 v0 = *(const float4*)p;
            float4 v1 = *(const float4*)(p + 4);
            breg[i][0] = v0.x; breg[i][1] = v0.y; breg[i][2] = v0.z; breg[i][3] = v0.w;
            breg[i][4] = v1.x; breg[i][5] = v1.y; breg[i][6] = v1.z; breg[i][7] = v1.w;
        }
    };
    auto stage_write = [&](int buf) {
#pragma unroll
        for (int i = 0; i < ACH; ++i) {
            int c = tid + i * 256;
            int row = c >> 2, ks = c & 3;
            B8 r;
            r.h[0] = __float22bfloat162_rn(float2{areg[i][0], areg[i][1]});
            r.h[1] = __float22bfloat162_rn(float2{areg[i][2], areg[i][3]});
            r.h[2] = __float22bfloat162_rn(float2{areg[i][4], areg[i][5]});
            r.h[3] = __float22bfloat162_rn(float2{areg[i][6], areg[i][7]});
            *(bf16x8*)&As[buf][row * LDST + ks * 8] = r.v;
        }
#pragma unroll
        for (int i = 0; i < BCH; ++i) {
            int c = tid + i * 256;
            int row = c >> 2, ks = c & 3;
            B8 r;
            r.h[0] = __float22bfloat162_rn(float2{breg[i][0], breg[i][1]});
            r.h[1] = __float22bfloat162_rn(float2{breg[i][2], breg[i][3]});
            r.h[2] = __float22bfloat162_rn(float2{breg[i][4], breg[i][5]});
            r.h[3] = __float22bfloat162_rn(float2{breg[i][6], breg[i][7]});
            *(bf16x8*)&Bs[buf][row * LDST + ks * 8] = r.v;
        }
    };

    stage_load(0);
    stage_write(0);
    __syncthreads();

    const int nk = K >> 5;
    int cur = 0;
    for (int s = 0; s < nk; ++s) {
        const bool more = (s + 1 < nk);
        if (more) stage_load((s + 1) << 5);

        bf16x8 af[MR], bf[NR];
#pragma unroll
        for (int mi = 0; mi < MR; ++mi)
            af[mi] = *(const bf16x8*)&As[cur][(wrow0 + mi * 16 + rc) * LDST + kgrp * 8];
#pragma unroll
        for (int ni = 0; ni < NR; ++ni)
            bf[ni] = *(const bf16x8*)&Bs[cur][(wcol0 + ni * 16 + rc) * LDST + kgrp * 8];
#pragma unroll
        for (int mi = 0; mi < MR; ++mi)
#pragma unroll
            for (int ni = 0; ni < NR; ++ni)
                acc[mi][ni] = __builtin_amdgcn_mfma_f32_16x16x32_bf16(
                    af[mi], bf[ni], acc[mi][ni], 0, 0, 0);

        if (more) stage_write(cur ^ 1);
        __syncthreads();
        cur ^= 1;
    }

#pragma unroll
    for (int mi = 0; mi < MR; ++mi) {
#pragma unroll
        for (int ni = 0; ni < NR; ++ni) {
            const int col = n0 + wcol0 + ni * 16 + rc;
            const int rbase = m0 + wrow0 + mi * 16 + kgrp * 4;
            float bv = bias ? bias[col] : 0.f;
#pragma unroll
            for (int i = 0; i < 4; ++i) {
                float v = acc[mi][ni][i] + bv;
                if (gelu_flag) v = 0.5f * v * (1.f + erff(v * 0.70710678118654752f));
                size_t idx = (size_t)(rbase + i) * N + col;
                if (Res) v += Res[idx];
                C[idx] = v;
            }
        }
    }
}

// ---------------------------------------------------------------------------
// MFMA attention. One block per (b, h, qtile of 64 rows); 4 waves, wave w
// owns 16 q-rows (= causal block qb = qt*4+w, kmax_w = (qb+1)*16).
// Swapped QK^T: S^T = mfma(K, Q*0.125) -> lane holds 4 consecutive kv per
// frag (frag-granular causal masking, 16-aligned). P packed to bf16 via
// cvt_pk -> ds_write_b64 (wave-local, no barrier) -> b128 A-frag for PV.
// V staged transposed (Vt[d][kv]) so PV B-frags are contiguous.
// ---------------------------------------------------------------------------
__global__ __launch_bounds__(256) void attn_mfma_kernel(
    const float* __restrict__ qkv, float* __restrict__ out)
{
    const int bid = blockIdx.x;            // 0..383, heavy qtiles first
    const int qt = 15 - (bid / 24);
    const int hb = bid % 24;
    const int h = hb % H_SZ, b = hb / H_SZ;
    const int tid = threadIdx.x;
    const int w = tid >> 6, lane = tid & 63;
    const int g = lane >> 4, r = lane & 15;

    constexpr int KS = 72;  // LDS row stride (shorts)
    __shared__ __align__(16) unsigned short Kl[64 * KS];
    __shared__ __align__(16) unsigned short Vt[64 * KS];
    __shared__ __align__(16) unsigned short Pl[4][16 * KS];

    const int tok0 = b * S_SZ + qt * 64;
    const int qrow0 = tok0 + w * 16;

    // Hoisted Q B-frags: lane holds q = r, d = ks*32 + g*8 + j. Scale folded.
    bf16x8 qf[2];
    {
        const float* qp = qkv + (size_t)(qrow0 + r) * (3 * D_SZ) + h * HD_SZ + g * 8;
#pragma unroll
        for (int ks = 0; ks < 2; ++ks) {
            float4 v0 = *(const float4*)(qp + ks * 32);
            float4 v1 = *(const float4*)(qp + ks * 32 + 4);
            B8 t;
            t.h[0] = __float22bfloat162_rn(float2{v0.x * 0.125f, v0.y * 0.125f});
            t.h[1] = __float22bfloat162_rn(float2{v0.z * 0.125f, v0.w * 0.125f});
            t.h[2] = __float22bfloat162_rn(float2{v1.x * 0.125f, v1.y * 0.125f});
            t.h[3] = __float22bfloat162_rn(float2{v1.z * 0.125f, v1.w * 0.125f});
            qf[ks] = t.v;
        }
    }

    float m_r = -1e30f, l_r = 0.f;
    f32x4 o[4];
#pragma unroll
    for (int ni = 0; ni < 4; ++ni) o[ni] = (f32x4){0.f, 0.f, 0.f, 0.f};

    const int kv_t = tid >> 2;            // staging: kv row 0..63
    const int d0_t = (tid & 3) * 16;      // staging: d chunk

    const int nchunk = qt + 1;
    for (int c = 0; c < nchunk; ++c) {
        __syncthreads();   // previous chunk's LDS reads complete
        // ---- stage K (vector) and V^T (scalar transposed) ----
        {
            const float* base = qkv + (size_t)(b * S_SZ + c * 64 + kv_t) * (3 * D_SZ)
                                    + h * HD_SZ + d0_t;
            float4 k0 = *(const float4*)(base + D_SZ);
            float4 k1 = *(const float4*)(base + D_SZ + 4);
            float4 k2 = *(const float4*)(base + D_SZ + 8);
            float4 k3 = *(const float4*)(base + D_SZ + 12);
            B8 p0, p1;
            p0.h[0] = __float22bfloat162_rn(float2{k0.x, k0.y});
            p0.h[1] = __float22bfloat162_rn(float2{k0.z, k0.w});
            p0.h[2] = __float22bfloat162_rn(float2{k1.x, k1.y});
            p0.h[3] = __float22bfloat162_rn(float2{k1.z, k1.w});
            p1.h[0] = __float22bfloat162_rn(float2{k2.x, k2.y});
            p1.h[1] = __float22bfloat162_rn(float2{k2.z, k2.w});
            p1.h[2] = __float22bfloat162_rn(float2{k3.x, k3.y});
            p1.h[3] = __float22bfloat162_rn(float2{k3.z, k3.w});
            *(bf16x8*)&Kl[kv_t * KS + d0_t]     = p0.v;
            *(bf16x8*)&Kl[kv_t * KS + d0_t + 8] = p1.v;

            float vv[16];
            float4 q0 = *(const float4*)(base + 2 * D_SZ);
            float4 q1 = *(const float4*)(base + 2 * D_SZ + 4);
            float4 q2 = *(const float4*)(base + 2 * D_SZ + 8);
            float4 q3 = *(const float4*)(base + 2 * D_SZ + 12);
            vv[0]=q0.x; vv[1]=q0.y; vv[2]=q0.z; vv[3]=q0.w;
            vv[4]=q1.x; vv[5]=q1.y; vv[6]=q1.z; vv[7]=q1.w;
            vv[8]=q2.x; vv[9]=q2.y; vv[10]=q2.z; vv[11]=q2.w;
            vv[12]=q3.x; vv[13]=q3.y; vv[14]=q3.z; vv[15]=q3.w;
#pragma unroll
            for (int di = 0; di < 16; ++di)
                Vt[(d0_t + di) * KS + kv_t] = f2bf(vv[di]);
        }
        __syncthreads();

        const bool lastc = (c == qt);
        const int mi_hi = lastc ? w : 3;   // inclusive valid frag bound

        // ---- S^T = K . Q^T : 4 m-frags (kv), 1 n-frag (q) ----
        f32x4 s[4];
#pragma unroll
        for (int mi = 0; mi < 4; ++mi) s[mi] = (f32x4){0.f, 0.f, 0.f, 0.f};
#pragma unroll
        for (int mi = 0; mi < 4; ++mi) {
            if (mi <= mi_hi) {
#pragma unroll
                for (int ks = 0; ks < 2; ++ks) {
                    bf16x8 af = *(const bf16x8*)&Kl[(16 * mi + r) * KS + 32 * ks + 8 * g];
                    s[mi] = __builtin_amdgcn_mfma_f32_16x16x32_bf16(af, qf[ks], s[mi], 0, 0, 0);
                }
            }
        }

        // ---- online softmax (per q-row = lane&15; reduce regs + g-groups) ----
        float mx = -1e30f;
#pragma unroll
        for (int mi = 0; mi < 4; ++mi) {
            if (mi <= mi_hi) {
#pragma unroll
                for (int i = 0; i < 4; ++i) mx = fmaxf(mx, s[mi][i]);
            }
        }
        mx = fmaxf(mx, __shfl_xor(mx, 16));
        mx = fmaxf(mx, __shfl_xor(mx, 32));
        float m_new = fmaxf(m_r, mx);
        float corr = __expf(m_r - m_new);

        float p[4][4];
        float psum = 0.f;
#pragma unroll
        for (int mi = 0; mi < 4; ++mi) {
#pragma unroll
            for (int i = 0; i < 4; ++i) {
                float pv = (mi <= mi_hi) ? __expf(s[mi][i] - m_new) : 0.f;
                p[mi][i] = pv;
                psum += pv;
            }
        }
        psum += __shfl_xor(psum, 16);
        psum += __shfl_xor(psum, 32);
        l_r = l_r * corr + psum;
        m_r = m_new;

        // ---- P -> bf16 -> LDS (wave-local; 4 x ds_write_b64) ----
#pragma unroll
        for (int mi = 0; mi < 4; ++mi) {
            B4 t;
            t.h[0] = __float22bfloat162_rn(float2{p[mi][0], p[mi][1]});
            t.h[1] = __float22bfloat162_rn(float2{p[mi][2], p[mi][3]});
            *(bf16x4*)&Pl[w][r * KS + 16 * mi + 4 * g] = t.v;
        }

        // ---- rescale O by corr (per O-row q = 4g+i) ----
        float co[4];
#pragma unroll
        for (int i = 0; i < 4; ++i) co[i] = __shfl(corr, 4 * g + i);
#pragma unroll
        for (int ni = 0; ni < 4; ++ni)
#pragma unroll
            for (int i = 0; i < 4; ++i) o[ni][i] *= co[i];

        // ---- PV: O += P . V  (A = P from LDS, B = Vt rows) ----
#pragma unroll
        for (int ks = 0; ks < 2; ++ks) {
            if (!lastc || 2 * ks <= w) {
                bf16x8 pf = *(const bf16x8*)&Pl[w][r * KS + 32 * ks + 8 * g];
#pragma unroll
                for (int ni = 0; ni < 4; ++ni) {
                    bf16x8 vf = *(const bf16x8*)&Vt[(r + 16 * ni) * KS + 32 * ks + 8 * g];
                    o[ni] = __builtin_amdgcn_mfma_f32_16x16x32_bf16(pf, vf, o[ni], 0, 0, 0);
                }
            }
        }
    }

    // ---- finalize: divide by row sums, store ----
    float inv[4];
#pragma unroll
    for (int i = 0; i < 4; ++i) {
        float lq = __shfl(l_r, 4 * g + i);
        inv[i] = 1.f / lq;
    }
#pragma unroll
    for (int ni = 0; ni < 4; ++ni) {
#pragma unroll
        for (int i = 0; i < 4; ++i) {
            out[(size_t)(qrow0 + 4 * g + i) * D_SZ + h * HD_SZ + r + 16 * ni]
                = o[ni][i] * inv[i];
        }
    }
}

// ---------------------------------------------------------------------------
// Per-row CE + final reduce (unchanged)
// ---------------------------------------------------------------------------
__global__ __launch_bounds__(256) void ce_kernel(
    const float* __restrict__ logits, const int* __restrict__ tgt,
    const int* __restrict__ inp, const float* __restrict__ noise,
    float* __restrict__ ce_row, float* __restrict__ msk_row)
{
    const int row = blockIdx.x;
    const int t = threadIdx.x;
    const float* lr = logits + (size_t)row * V_SZ;
    __shared__ float red[256];

    float mx = -1e30f;
    for (int i = t; i < V_SZ; i += 256) mx = fmaxf(mx, lr[i]);
    red[t] = mx;
    __syncthreads();
    for (int off = 128; off; off >>= 1) {
        if (t < off) red[t] = fmaxf(red[t], red[t + off]);
        __syncthreads();
    }
    float M = red[0];
    __syncthreads();
    float s = 0.f;
    for (int i = t; i < V_SZ; i += 256) s += expf(lr[i] - M);
    red[t] = s;
    __syncthreads();
    for (int off = 128; off; off >>= 1) {
        if (t < off) red[t] += red[t + off];
        __syncthreads();
    }
    if (t == 0) {
        int tg = tgt[row];
        float ce = -(lr[tg] - M - logf(red[0]));
        int ism = (inp[row] == MASK_ID) ? 1 : 0;
        int b = row / S_SZ;
        ce_row[row] = ism ? (ce / noise[b]) : 0.f;
        msk_row[row] = ism ? 1.f : 0.f;
    }
}

__global__ __launch_bounds__(256) void loss_reduce_kernel(
    const float* __restrict__ ce_row, const float* __restrict__ msk_row,
    float* __restrict__ out0)
{
    const int t = threadIdx.x;
    __shared__ float r1[256], r2[256];
    float s = 0.f, c = 0.f;
    for (int i = t; i < NTOK; i += 256) { s += ce_row[i]; c += msk_row[i]; }
    r1[t] = s; r2[t] = c;
    __syncthreads();
    for (int off = 128; off; off >>= 1) {
        if (t < off) { r1[t] += r1[t + off]; r2[t] += r2[t + off]; }
        __syncthreads();
    }
    if (t == 0) out0[0] = r1[0] / (r2[0] + 1e-8f);
}

// ---------------------------------------------------------------------------
// Host launch
// ---------------------------------------------------------------------------
extern "C" void kernel_launch(void* const* d_in, const int* in_sizes, int n_in,
                              void* d_out, int out_size, void* d_ws, size_t ws_size,
                              hipStream_t stream)
{
    const int*   input_ids  = (const int*)d_in[0];
    const int*   target_ids = (const int*)d_in[1];
    const float* noise      = (const float*)d_in[2];
    const float* emb        = (const float*)d_in[3];
    const float* in_w       = (const float*)d_in[4];
    const float* in_b       = (const float*)d_in[5];
    const float* aow        = (const float*)d_in[6];
    const float* aob        = (const float*)d_in[7];
    const float* ln1w       = (const float*)d_in[8];
    const float* ln1b       = (const float*)d_in[9];
    const float* ln2w       = (const float*)d_in[10];
    const float* ln2b       = (const float*)d_in[11];
    const float* w1         = (const float*)d_in[12];
    const float* b1         = (const float*)d_in[13];
    const float* w2         = (const float*)d_in[14];
    const float* b2         = (const float*)d_in[15];
    const float* projw      = (const float*)d_in[16];
    const float* projb      = (const float*)d_in[17];

    float* out    = (float*)d_out;
    float* logits = out + 1;                       // [2048][32000]

    // Large per-layer scratch in the tail of d_out (dead before logits GEMM)
    float* mid  = out + 51380224;   // [2048][3072]
    float* qkv  = out + 57671680;   // [2048][2304]
    float* hbuf = out + 62390272;   // [2048][768]
    float* ao   = out + 63963136;   // [2048][768]

    float* x       = (float*)d_ws;                 // [2048][768], survives logits
    float* ce_row  = x + (size_t)NTOK * D_SZ;
    float* msk_row = ce_row + NTOK;

    embed_rot_kernel<<<NTOK, 256, 0, stream>>>(input_ids, emb, x);

    for (int l = 0; l < L_SZ; ++l) {
        ln_kernel<<<NTOK, 256, 0, stream>>>(x, ln1w + l * D_SZ, ln1b + l * D_SZ, hbuf);
        mfma_gemm<128, 128><<<dim3(18, 16), 256, 0, stream>>>(
            hbuf, in_w + (size_t)l * 3 * D_SZ * D_SZ, in_b + (size_t)l * 3 * D_SZ,
            nullptr, qkv, NTOK, 3 * D_SZ, D_SZ, 0);
        attn_mfma_kernel<<<B_SZ * H_SZ * 16, 256, 0, stream>>>(qkv, ao);
        mfma_gemm<64, 128><<<dim3(6, 32), 256, 0, stream>>>(
            ao, aow + (size_t)l * D_SZ * D_SZ, aob + (size_t)l * D_SZ,
            x, x, NTOK, D_SZ, D_SZ, 0);
        ln_kernel<<<NTOK, 256, 0, stream>>>(x, ln2w + l * D_SZ, ln2b + l * D_SZ, hbuf);
        mfma_gemm<128, 128><<<dim3(24, 16), 256, 0, stream>>>(
            hbuf, w1 + (size_t)l * DF_SZ * D_SZ, b1 + (size_t)l * DF_SZ,
            nullptr, mid, NTOK, DF_SZ, D_SZ, 1);
        mfma_gemm<64, 128><<<dim3(6, 32), 256, 0, stream>>>(
            mid, w2 + (size_t)l * D_SZ * DF_SZ, b2 + (size_t)l * D_SZ,
            x, x, NTOK, D_SZ, DF_SZ, 0);
    }

    mfma_gemm<128, 128><<<dim3(250, 16), 256, 0, stream>>>(
        x, projw, projb, nullptr, logits, NTOK, V_SZ, D_SZ, 0);

    ce_kernel<<<NTOK, 256, 0, stream>>>(logits, target_ids, input_ids, noise,
                                        ce_row, msk_row);
    loss_reduce_kernel<<<1, 256, 0, stream>>>(ce_row, msk_row, out);
}

// Round 4
// 2956.144 us; speedup vs baseline: 5.0129x; 1.0463x over previous
//
#include <hip/hip_runtime.h>
#include <hip/hip_bf16.h>
#include <math.h>

// Problem constants
#define V_SZ 32000
#define D_SZ 768
#define H_SZ 12
#define L_SZ 12
#define DF_SZ 3072
#define B_SZ 2
#define S_SZ 1024
#define BS_SZ 16
#define HD_SZ 64
#define MASK_ID 31999
#define NTOK (B_SZ * S_SZ)   // 2048

typedef __attribute__((ext_vector_type(8))) short bf16x8;
typedef __attribute__((ext_vector_type(4))) short bf16x4;
typedef __attribute__((ext_vector_type(4))) float f32x4;

union B8 { bf16x8 v; __hip_bfloat162 h[4]; };
union B4 { bf16x4 v; __hip_bfloat162 h[2]; };
union U4 { ushort4 u; __hip_bfloat162 h[2]; };

__device__ inline unsigned short f2bf(float x) {
    __hip_bfloat16 b = __float2bfloat16(x);
    union { __hip_bfloat16 b; unsigned short u; } c; c.b = b;
    return c.u;
}

// ---------------------------------------------------------------------------
// Weight conversion: fold ln scale into W rows, ln bias into GEMM bias.
// One wave per row (K = 768). Wdst[row][k] = bf16(W[row][k] * lnw[k]);
// bdst[row] = bsrc[row] + sum_k lnb[k] * W[row][k].
// ---------------------------------------------------------------------------
__global__ __launch_bounds__(256) void conv_fold_kernel(
    const float* __restrict__ Wsrc, const float* __restrict__ lnw,
    const float* __restrict__ lnb, const float* __restrict__ bsrc,
    unsigned short* __restrict__ Wdst, float* __restrict__ bdst,
    int rows_per_layer)
{
    const int gw = (blockIdx.x * 256 + threadIdx.x) >> 6;
    const int lane = threadIdx.x & 63;
    const int l = gw / rows_per_layer;
    const float* src = Wsrc + (size_t)gw * D_SZ;
    const float* wv = lnw + l * D_SZ;
    const float* bv = lnb + l * D_SZ;
    unsigned short* dst = Wdst + (size_t)gw * D_SZ;
    float acc = 0.f;
#pragma unroll
    for (int j = 0; j < 3; ++j) {
        int k = lane * 4 + j * 256;
        float4 s = *(const float4*)(src + k);
        float4 w = *(const float4*)(wv + k);
        float4 bb = *(const float4*)(bv + k);
        acc += bb.x * s.x + bb.y * s.y + bb.z * s.z + bb.w * s.w;
        U4 o;
        o.h[0] = __float22bfloat162_rn(float2{s.x * w.x, s.y * w.y});
        o.h[1] = __float22bfloat162_rn(float2{s.z * w.z, s.w * w.w});
        *(ushort4*)(dst + k) = o.u;
    }
#pragma unroll
    for (int off = 32; off; off >>= 1) acc += __shfl_xor(acc, off);
    if (lane == 0) bdst[gw] = bsrc[gw] + acc;
}

// Plain f32 -> bf16 cast, 8 elems/thread
__global__ __launch_bounds__(256) void conv_cast_kernel(
    const float* __restrict__ src, unsigned short* __restrict__ dst, int n8)
{
    int i = blockIdx.x * 256 + threadIdx.x;
    if (i >= n8) return;
    const float* p = src + (size_t)i * 8;
    float4 v0 = *(const float4*)p;
    float4 v1 = *(const float4*)(p + 4);
    B8 r;
    r.h[0] = __float22bfloat162_rn(float2{v0.x, v0.y});
    r.h[1] = __float22bfloat162_rn(float2{v0.z, v0.w});
    r.h[2] = __float22bfloat162_rn(float2{v1.x, v1.y});
    r.h[3] = __float22bfloat162_rn(float2{v1.z, v1.w});
    *(bf16x8*)(dst + (size_t)i * 8) = r.v;
}

// ---------------------------------------------------------------------------
// Embedding gather + rotary
// ---------------------------------------------------------------------------
__global__ __launch_bounds__(256) void embed_rot_kernel(
    const int* __restrict__ ids, const float* __restrict__ emb,
    float* __restrict__ x)
{
    const int tok = blockIdx.x;
    const int s = tok & (S_SZ - 1);
    const int id = ids[tok];
    const float* e = emb + (size_t)id * D_SZ;
    float* xo = x + (size_t)tok * D_SZ;
    const int t = threadIdx.x;

    if (t < 192) {
        float x0 = e[2 * t], x1 = e[2 * t + 1];
        float freq = powf(10000.f, -((float)(2 * t)) / 384.f);
        float ang = (float)s * freq;
        float sn, cs;
        sincosf(ang, &sn, &cs);
        xo[2 * t]     = x0 * cs - x1 * sn;
        xo[2 * t + 1] = x0 * sn + x1 * cs;
    }
    for (int ch = 384 + t; ch < D_SZ; ch += 256) xo[ch] = e[ch];
}

// ---------------------------------------------------------------------------
// MFMA bf16 GEMM: C[M,N] = act(opA(A)[M,K] @ W[N,K]^T + bias) [+ Res]
//  WB16: W is pre-converted bf16 row-major [N][K]
//  LNF:  A is raw x; in-block stats pre-pass computes per-row mean/rstd,
//        staging applies (v - mu) * rstd during f32->bf16 pack (ln scale/bias
//        folded into W/bias at conversion time). Requires BM == 64 usage here.
// Grid: dim3(M/BM, N/BN) -- m fastest => consecutive blocks share W n-strip.
// ---------------------------------------------------------------------------
template<int BM, int BN, bool WB16, bool LNF>
__global__ __launch_bounds__(256) void mfma_gemm(
    const float* __restrict__ A, const void* __restrict__ Wv,
    const float* __restrict__ bias, const float* __restrict__ Res,
    float* __restrict__ C, int M, int N, int K, int gelu_flag)
{
    constexpr int LDST = 40;            // bf16 per LDS row (32 + 8 pad)
    constexpr int MR = BM / 32;
    constexpr int NR = BN / 32;
    constexpr int ACH = BM * 4 / 256;
    constexpr int BCH = BN * 4 / 256;

    __shared__ __align__(16) unsigned short As[2][BM * LDST];
    __shared__ __align__(16) unsigned short Bs[2][BN * LDST];
    __shared__ float smean[LNF ? BM : 1];
    __shared__ float srstd[LNF ? BM : 1];

    const int tid = threadIdx.x;
    const int lane = tid & 63;
    const int wave = tid >> 6;
    const int wrow0 = (wave >> 1) * (BM / 2);
    const int wcol0 = (wave & 1) * (BN / 2);
    const int kgrp = lane >> 4;
    const int rc = lane & 15;

    const int m0 = blockIdx.x * BM;
    const int n0 = blockIdx.y * BN;

    // ---- LN stats pre-pass: 4 threads per row ----
    if constexpr (LNF) {
        const int row = tid >> 2, q = tid & 3;
        const float* xr = A + (size_t)(m0 + row) * K + q * (K >> 2);
        float sum = 0.f, ss = 0.f;
        for (int j = 0; j < (K >> 4); ++j) {
            float4 v = *(const float4*)(xr + j * 4);
            sum += v.x + v.y + v.z + v.w;
            ss += v.x * v.x + v.y * v.y + v.z * v.z + v.w * v.w;
        }
        sum += __shfl_xor(sum, 1); sum += __shfl_xor(sum, 2);
        ss  += __shfl_xor(ss, 1);  ss  += __shfl_xor(ss, 2);
        float mean = sum * (1.f / (float)K);
        float var = ss * (1.f / (float)K) - mean * mean;
        if (q == 0) { smean[row] = mean; srstd[row] = rsqrtf(var + 1e-5f); }
        __syncthreads();
    }

    f32x4 acc[MR][NR];
#pragma unroll
    for (int i = 0; i < MR; ++i)
#pragma unroll
        for (int j = 0; j < NR; ++j) acc[i][j] = (f32x4){0.f, 0.f, 0.f, 0.f};

    float areg[ACH][8];
    float bregf[WB16 ? 1 : BCH][WB16 ? 1 : 8];
    bf16x8 breg16[WB16 ? BCH : 1];

    auto stage_load = [&](int k0) {
#pragma unroll
        for (int i = 0; i < ACH; ++i) {
            int c = tid + i * 256;
            int row = c >> 2, ks = c & 3;
            const float* p = A + (size_t)(m0 + row) * K + k0 + ks * 8;
            float4 v0 = *(const float4*)p;
            float4 v1 = *(const float4*)(p + 4);
            areg[i][0] = v0.x; areg[i][1] = v0.y; areg[i][2] = v0.z; areg[i][3] = v0.w;
            areg[i][4] = v1.x; areg[i][5] = v1.y; areg[i][6] = v1.z; areg[i][7] = v1.w;
        }
        if constexpr (WB16) {
            const unsigned short* W16 = (const unsigned short*)Wv;
#pragma unroll
            for (int i = 0; i < BCH; ++i) {
                int c = tid + i * 256;
                int row = c >> 2, ks = c & 3;
                breg16[i] = *(const bf16x8*)(W16 + (size_t)(n0 + row) * K + k0 + ks * 8);
            }
        } else {
            const float* Wf = (const float*)Wv;
#pragma unroll
            for (int i = 0; i < BCH; ++i) {
                int c = tid + i * 256;
                int row = c >> 2, ks = c & 3;
                const float* p = Wf + (size_t)(n0 + row) * K + k0 + ks * 8;
                float4 v0 = *(const float4*)p;
                float4 v1 = *(const float4*)(p + 4);
                bregf[i][0] = v0.x; bregf[i][1] = v0.y; bregf[i][2] = v0.z; bregf[i][3] = v0.w;
                bregf[i][4] = v1.x; bregf[i][5] = v1.y; bregf[i][6] = v1.z; bregf[i][7] = v1.w;
            }
        }
    };
    auto stage_write = [&](int buf) {
#pragma unroll
        for (int i = 0; i < ACH; ++i) {
            int c = tid + i * 256;
            int row = c >> 2, ks = c & 3;
            float sc = 1.f, sh = 0.f;
            if constexpr (LNF) { sc = srstd[row]; sh = -smean[row] * sc; }
            B8 r;
            r.h[0] = __float22bfloat162_rn(float2{fmaf(areg[i][0], sc, sh), fmaf(areg[i][1], sc, sh)});
            r.h[1] = __float22bfloat162_rn(float2{fmaf(areg[i][2], sc, sh), fmaf(areg[i][3], sc, sh)});
            r.h[2] = __float22bfloat162_rn(float2{fmaf(areg[i][4], sc, sh), fmaf(areg[i][5], sc, sh)});
            r.h[3] = __float22bfloat162_rn(float2{fmaf(areg[i][6], sc, sh), fmaf(areg[i][7], sc, sh)});
            *(bf16x8*)&As[buf][row * LDST + ks * 8] = r.v;
        }
#pragma unroll
        for (int i = 0; i < BCH; ++i) {
            int c = tid + i * 256;
            int row = c >> 2, ks = c & 3;
            if constexpr (WB16) {
                *(bf16x8*)&Bs[buf][row * LDST + ks * 8] = breg16[i];
            } else {
                B8 r;
                r.h[0] = __float22bfloat162_rn(float2{bregf[i][0], bregf[i][1]});
                r.h[1] = __float22bfloat162_rn(float2{bregf[i][2], bregf[i][3]});
                r.h[2] = __float22bfloat162_rn(float2{bregf[i][4], bregf[i][5]});
                r.h[3] = __float22bfloat162_rn(float2{bregf[i][6], bregf[i][7]});
                *(bf16x8*)&Bs[buf][row * LDST + ks * 8] = r.v;
            }
        }
    };

    stage_load(0);
    stage_write(0);
    __syncthreads();

    const int nk = K >> 5;
    int cur = 0;
    for (int s = 0; s < nk; ++s) {
        const bool more = (s + 1 < nk);
        if (more) stage_load((s + 1) << 5);

        bf16x8 af[MR], bf[NR];
#pragma unroll
        for (int mi = 0; mi < MR; ++mi)
            af[mi] = *(const bf16x8*)&As[cur][(wrow0 + mi * 16 + rc) * LDST + kgrp * 8];
#pragma unroll
        for (int ni = 0; ni < NR; ++ni)
            bf[ni] = *(const bf16x8*)&Bs[cur][(wcol0 + ni * 16 + rc) * LDST + kgrp * 8];
#pragma unroll
        for (int mi = 0; mi < MR; ++mi)
#pragma unroll
            for (int ni = 0; ni < NR; ++ni)
                acc[mi][ni] = __builtin_amdgcn_mfma_f32_16x16x32_bf16(
                    af[mi], bf[ni], acc[mi][ni], 0, 0, 0);

        if (more) stage_write(cur ^ 1);
        __syncthreads();
        cur ^= 1;
    }

#pragma unroll
    for (int mi = 0; mi < MR; ++mi) {
#pragma unroll
        for (int ni = 0; ni < NR; ++ni) {
            const int col = n0 + wcol0 + ni * 16 + rc;
            const int rbase = m0 + wrow0 + mi * 16 + kgrp * 4;
            float bv = bias ? bias[col] : 0.f;
#pragma unroll
            for (int i = 0; i < 4; ++i) {
                float v = acc[mi][ni][i] + bv;
                if (gelu_flag) v = 0.5f * v * (1.f + erff(v * 0.70710678118654752f));
                size_t idx = (size_t)(rbase + i) * N + col;
                if (Res) v += Res[idx];
                C[idx] = v;
            }
        }
    }
}

// ---------------------------------------------------------------------------
// MFMA attention (unchanged from round 3)
// ---------------------------------------------------------------------------
__global__ __launch_bounds__(256) void attn_mfma_kernel(
    const float* __restrict__ qkv, float* __restrict__ out)
{
    const int bid = blockIdx.x;
    const int qt = 15 - (bid / 24);
    const int hb = bid % 24;
    const int h = hb % H_SZ, b = hb / H_SZ;
    const int tid = threadIdx.x;
    const int w = tid >> 6, lane = tid & 63;
    const int g = lane >> 4, r = lane & 15;

    constexpr int KS = 72;
    __shared__ __align__(16) unsigned short Kl[64 * KS];
    __shared__ __align__(16) unsigned short Vt[64 * KS];
    __shared__ __align__(16) unsigned short Pl[4][16 * KS];

    const int qrow0 = b * S_SZ + qt * 64 + w * 16;

    bf16x8 qf[2];
    {
        const float* qp = qkv + (size_t)(qrow0 + r) * (3 * D_SZ) + h * HD_SZ + g * 8;
#pragma unroll
        for (int ks = 0; ks < 2; ++ks) {
            float4 v0 = *(const float4*)(qp + ks * 32);
            float4 v1 = *(const float4*)(qp + ks * 32 + 4);
            B8 t;
            t.h[0] = __float22bfloat162_rn(float2{v0.x * 0.125f, v0.y * 0.125f});
            t.h[1] = __float22bfloat162_rn(float2{v0.z * 0.125f, v0.w * 0.125f});
            t.h[2] = __float22bfloat162_rn(float2{v1.x * 0.125f, v1.y * 0.125f});
            t.h[3] = __float22bfloat162_rn(float2{v1.z * 0.125f, v1.w * 0.125f});
            qf[ks] = t.v;
        }
    }

    float m_r = -1e30f, l_r = 0.f;
    f32x4 o[4];
#pragma unroll
    for (int ni = 0; ni < 4; ++ni) o[ni] = (f32x4){0.f, 0.f, 0.f, 0.f};

    const int kv_t = tid >> 2;
    const int d0_t = (tid & 3) * 16;

    const int nchunk = qt + 1;
    for (int c = 0; c < nchunk; ++c) {
        __syncthreads();
        {
            const float* base = qkv + (size_t)(b * S_SZ + c * 64 + kv_t) * (3 * D_SZ)
                                    + h * HD_SZ + d0_t;
            float4 k0 = *(const float4*)(base + D_SZ);
            float4 k1 = *(const float4*)(base + D_SZ + 4);
            float4 k2 = *(const float4*)(base + D_SZ + 8);
            float4 k3 = *(const float4*)(base + D_SZ + 12);
            B8 p0, p1;
            p0.h[0] = __float22bfloat162_rn(float2{k0.x, k0.y});
            p0.h[1] = __float22bfloat162_rn(float2{k0.z, k0.w});
            p0.h[2] = __float22bfloat162_rn(float2{k1.x, k1.y});
            p0.h[3] = __float22bfloat162_rn(float2{k1.z, k1.w});
            p1.h[0] = __float22bfloat162_rn(float2{k2.x, k2.y});
            p1.h[1] = __float22bfloat162_rn(float2{k2.z, k2.w});
            p1.h[2] = __float22bfloat162_rn(float2{k3.x, k3.y});
            p1.h[3] = __float22bfloat162_rn(float2{k3.z, k3.w});
            *(bf16x8*)&Kl[kv_t * KS + d0_t]     = p0.v;
            *(bf16x8*)&Kl[kv_t * KS + d0_t + 8] = p1.v;

            float vv[16];
            float4 q0 = *(const float4*)(base + 2 * D_SZ);
            float4 q1 = *(const float4*)(base + 2 * D_SZ + 4);
            float4 q2 = *(const float4*)(base + 2 * D_SZ + 8);
            float4 q3 = *(const float4*)(base + 2 * D_SZ + 12);
            vv[0]=q0.x; vv[1]=q0.y; vv[2]=q0.z; vv[3]=q0.w;
            vv[4]=q1.x; vv[5]=q1.y; vv[6]=q1.z; vv[7]=q1.w;
            vv[8]=q2.x; vv[9]=q2.y; vv[10]=q2.z; vv[11]=q2.w;
            vv[12]=q3.x; vv[13]=q3.y; vv[14]=q3.z; vv[15]=q3.w;
#pragma unroll
            for (int di = 0; di < 16; ++di)
                Vt[(d0_t + di) * KS + kv_t] = f2bf(vv[di]);
        }
        __syncthreads();

        const bool lastc = (c == qt);
        const int mi_hi = lastc ? w : 3;

        f32x4 s[4];
#pragma unroll
        for (int mi = 0; mi < 4; ++mi) s[mi] = (f32x4){0.f, 0.f, 0.f, 0.f};
#pragma unroll
        for (int mi = 0; mi < 4; ++mi) {
            if (mi <= mi_hi) {
#pragma unroll
                for (int ks = 0; ks < 2; ++ks) {
                    bf16x8 af = *(const bf16x8*)&Kl[(16 * mi + r) * KS + 32 * ks + 8 * g];
                    s[mi] = __builtin_amdgcn_mfma_f32_16x16x32_bf16(af, qf[ks], s[mi], 0, 0, 0);
                }
            }
        }

        float mx = -1e30f;
#pragma unroll
        for (int mi = 0; mi < 4; ++mi) {
            if (mi <= mi_hi) {
#pragma unroll
                for (int i = 0; i < 4; ++i) mx = fmaxf(mx, s[mi][i]);
            }
        }
        mx = fmaxf(mx, __shfl_xor(mx, 16));
        mx = fmaxf(mx, __shfl_xor(mx, 32));
        float m_new = fmaxf(m_r, mx);
        float corr = __expf(m_r - m_new);

        float p[4][4];
        float psum = 0.f;
#pragma unroll
        for (int mi = 0; mi < 4; ++mi) {
#pragma unroll
            for (int i = 0; i < 4; ++i) {
                float pv = (mi <= mi_hi) ? __expf(s[mi][i] - m_new) : 0.f;
                p[mi][i] = pv;
                psum += pv;
            }
        }
        psum += __shfl_xor(psum, 16);
        psum += __shfl_xor(psum, 32);
        l_r = l_r * corr + psum;
        m_r = m_new;

#pragma unroll
        for (int mi = 0; mi < 4; ++mi) {
            B4 t;
            t.h[0] = __float22bfloat162_rn(float2{p[mi][0], p[mi][1]});
            t.h[1] = __float22bfloat162_rn(float2{p[mi][2], p[mi][3]});
            *(bf16x4*)&Pl[w][r * KS + 16 * mi + 4 * g] = t.v;
        }

        float co[4];
#pragma unroll
        for (int i = 0; i < 4; ++i) co[i] = __shfl(corr, 4 * g + i);
#pragma unroll
        for (int ni = 0; ni < 4; ++ni)
#pragma unroll
            for (int i = 0; i < 4; ++i) o[ni][i] *= co[i];

#pragma unroll
        for (int ks = 0; ks < 2; ++ks) {
            if (!lastc || 2 * ks <= w) {
                bf16x8 pf = *(const bf16x8*)&Pl[w][r * KS + 32 * ks + 8 * g];
#pragma unroll
                for (int ni = 0; ni < 4; ++ni) {
                    bf16x8 vf = *(const bf16x8*)&Vt[(r + 16 * ni) * KS + 32 * ks + 8 * g];
                    o[ni] = __builtin_amdgcn_mfma_f32_16x16x32_bf16(pf, vf, o[ni], 0, 0, 0);
                }
            }
        }
    }

    float inv[4];
#pragma unroll
    for (int i = 0; i < 4; ++i) {
        float lq = __shfl(l_r, 4 * g + i);
        inv[i] = 1.f / lq;
    }
#pragma unroll
    for (int ni = 0; ni < 4; ++ni) {
#pragma unroll
        for (int i = 0; i < 4; ++i) {
            out[(size_t)(qrow0 + 4 * g + i) * D_SZ + h * HD_SZ + r + 16 * ni]
                = o[ni][i] * inv[i];
        }
    }
}

// ---------------------------------------------------------------------------
// Per-row CE + final reduce
// ---------------------------------------------------------------------------
__global__ __launch_bounds__(256) void ce_kernel(
    const float* __restrict__ logits, const int* __restrict__ tgt,
    const int* __restrict__ inp, const float* __restrict__ noise,
    float* __restrict__ ce_row, float* __restrict__ msk_row)
{
    const int row = blockIdx.x;
    const int t = threadIdx.x;
    const float* lr = logits + (size_t)row * V_SZ;
    __shared__ float red[256];

    float mx = -1e30f;
    for (int i = t; i < V_SZ; i += 256) mx = fmaxf(mx, lr[i]);
    red[t] = mx;
    __syncthreads();
    for (int off = 128; off; off >>= 1) {
        if (t < off) red[t] = fmaxf(red[t], red[t + off]);
        __syncthreads();
    }
    float M = red[0];
    __syncthreads();
    float s = 0.f;
    for (int i = t; i < V_SZ; i += 256) s += expf(lr[i] - M);
    red[t] = s;
    __syncthreads();
    for (int off = 128; off; off >>= 1) {
        if (t < off) red[t] += red[t + off];
        __syncthreads();
    }
    if (t == 0) {
        int tg = tgt[row];
        float ce = -(lr[tg] - M - logf(red[0]));
        int ism = (inp[row] == MASK_ID) ? 1 : 0;
        int b = row / S_SZ;
        ce_row[row] = ism ? (ce / noise[b]) : 0.f;
        msk_row[row] = ism ? 1.f : 0.f;
    }
}

__global__ __launch_bounds__(256) void loss_reduce_kernel(
    const float* __restrict__ ce_row, const float* __restrict__ msk_row,
    float* __restrict__ out0)
{
    const int t = threadIdx.x;
    __shared__ float r1[256], r2[256];
    float s = 0.f, c = 0.f;
    for (int i = t; i < NTOK; i += 256) { s += ce_row[i]; c += msk_row[i]; }
    r1[t] = s; r2[t] = c;
    __syncthreads();
    for (int off = 128; off; off >>= 1) {
        if (t < off) { r1[t] += r1[t + off]; r2[t] += r2[t + off]; }
        __syncthreads();
    }
    if (t == 0) out0[0] = r1[0] / (r2[0] + 1e-8f);
}

// ---------------------------------------------------------------------------
// Host launch
// ---------------------------------------------------------------------------
extern "C" void kernel_launch(void* const* d_in, const int* in_sizes, int n_in,
                              void* d_out, int out_size, void* d_ws, size_t ws_size,
                              hipStream_t stream)
{
    const int*   input_ids  = (const int*)d_in[0];
    const int*   target_ids = (const int*)d_in[1];
    const float* noise      = (const float*)d_in[2];
    const float* emb        = (const float*)d_in[3];
    const float* in_w       = (const float*)d_in[4];
    const float* in_b       = (const float*)d_in[5];
    const float* aow        = (const float*)d_in[6];
    const float* aob        = (const float*)d_in[7];
    const float* ln1w       = (const float*)d_in[8];
    const float* ln1b       = (const float*)d_in[9];
    const float* ln2w       = (const float*)d_in[10];
    const float* ln2b       = (const float*)d_in[11];
    const float* w1         = (const float*)d_in[12];
    const float* b1         = (const float*)d_in[13];
    const float* w2         = (const float*)d_in[14];
    const float* b2         = (const float*)d_in[15];
    const float* projw      = (const float*)d_in[16];
    const float* projb      = (const float*)d_in[17];

    float* out    = (float*)d_out;
    float* logits = out + 1;                       // [2048][32000]

    // --- scratch inside d_out (dead before the logits GEMM writes) ---
    // float-slot offsets from base = out + 4 (16B aligned)
    float* base = out + 4;
    unsigned short* wq16 = (unsigned short*)(base);               // 12x2304x768 bf16
    unsigned short* wa16 = (unsigned short*)(base + 10616832);    // 12x768x768
    unsigned short* w116 = (unsigned short*)(base + 14155776);    // 12x3072x768
    unsigned short* w216 = (unsigned short*)(base + 28311552);    // 12x768x3072
    float* qkvb2 = base + 42467328;                               // 12x2304
    float* b1b2  = qkvb2 + 27648;                                 // 12x3072
    float* mid   = b1b2 + 36864;                                  // [2048][3072]
    float* qkvbuf= mid + 6291456;                                 // [2048][2304]
    float* aobuf = qkvbuf + 4718592;                              // [2048][768]
    // total end: 4 + 55,114,752 < 65,536,001 ✓

    // --- d_ws: x (survives logits GEMM) + CE rows + optional bf16 projw ---
    float* x       = (float*)d_ws;                 // [2048][768]
    float* ce_row  = x + (size_t)NTOK * D_SZ;
    float* msk_row = ce_row + NTOK;
    unsigned short* projw16 = (unsigned short*)(msk_row + NTOK);
    const bool pw16 = ws_size >= (size_t)(NTOK * D_SZ + 2 * NTOK) * 4
                                + (size_t)V_SZ * D_SZ * 2;

    // --- one-time weight conversions ---
    conv_fold_kernel<<<6912, 256, 0, stream>>>(in_w, ln1w, ln1b, in_b, wq16, qkvb2, 2304);
    conv_fold_kernel<<<9216, 256, 0, stream>>>(w1, ln2w, ln2b, b1, w116, b1b2, 3072);
    conv_cast_kernel<<<3456, 256, 0, stream>>>(aow, wa16, 884736);
    conv_cast_kernel<<<13824, 256, 0, stream>>>(w2, w216, 3538944);
    if (pw16)
        conv_cast_kernel<<<12000, 256, 0, stream>>>(projw, projw16, 3072000);

    embed_rot_kernel<<<NTOK, 256, 0, stream>>>(input_ids, emb, x);

    for (int l = 0; l < L_SZ; ++l) {
        mfma_gemm<64, 128, true, true><<<dim3(32, 18), 256, 0, stream>>>(
            x, wq16 + (size_t)l * 1769472, qkvb2 + l * 2304,
            nullptr, qkvbuf, NTOK, 2304, 768, 0);
        attn_mfma_kernel<<<B_SZ * H_SZ * 16, 256, 0, stream>>>(qkvbuf, aobuf);
        mfma_gemm<64, 64, true, false><<<dim3(32, 12), 256, 0, stream>>>(
            aobuf, wa16 + (size_t)l * 589824, aob + l * D_SZ,
            x, x, NTOK, 768, 768, 0);
        mfma_gemm<64, 128, true, true><<<dim3(32, 24), 256, 0, stream>>>(
            x, w116 + (size_t)l * 2359296, b1b2 + l * 3072,
            nullptr, mid, NTOK, 3072, 768, 1);
        mfma_gemm<64, 64, true, false><<<dim3(32, 12), 256, 0, stream>>>(
            mid, w216 + (size_t)l * 2359296, b2 + l * D_SZ,
            x, x, NTOK, 768, 3072, 0);
    }

    if (pw16) {
        mfma_gemm<128, 128, true, false><<<dim3(16, 250), 256, 0, stream>>>(
            x, projw16, projb, nullptr, logits, NTOK, V_SZ, 768, 0);
    } else {
        mfma_gemm<128, 128, false, false><<<dim3(16, 250), 256, 0, stream>>>(
            x, projw, projb, nullptr, logits, NTOK, V_SZ, 768, 0);
    }

    ce_kernel<<<NTOK, 256, 0, stream>>>(logits, target_ids, input_ids, noise,
                                        ce_row, msk_row);
    loss_reduce_kernel<<<1, 256, 0, stream>>>(ce_row, msk_row, out);
}

// Round 5
// 2766.475 us; speedup vs baseline: 5.3566x; 1.0686x over previous
//
#include <hip/hip_runtime.h>
#include <hip/hip_bf16.h>
#include <math.h>

// Problem constants
#define V_SZ 32000
#define D_SZ 768
#define H_SZ 12
#define L_SZ 12
#define DF_SZ 3072
#define B_SZ 2
#define S_SZ 1024
#define BS_SZ 16
#define HD_SZ 64
#define MASK_ID 31999
#define NTOK (B_SZ * S_SZ)   // 2048

typedef __attribute__((ext_vector_type(8))) short bf16x8;
typedef __attribute__((ext_vector_type(4))) short bf16x4;
typedef __attribute__((ext_vector_type(4))) float f32x4;

union B8 { bf16x8 v; __hip_bfloat162 h[4]; };
union B4 { bf16x4 v; __hip_bfloat162 h[2]; };
union U4 { ushort4 u; __hip_bfloat162 h[2]; };
union U4E { ushort4 u; unsigned short e[4]; };

__device__ inline unsigned short f2bf(float x) {
    __hip_bfloat16 b = __float2bfloat16(x);
    union { __hip_bfloat16 b; unsigned short u; } c; c.b = b;
    return c.u;
}

// ---------------------------------------------------------------------------
// Weight conversion: fold ln scale into W rows, ln bias into GEMM bias.
// ---------------------------------------------------------------------------
__global__ __launch_bounds__(256) void conv_fold_kernel(
    const float* __restrict__ Wsrc, const float* __restrict__ lnw,
    const float* __restrict__ lnb, const float* __restrict__ bsrc,
    unsigned short* __restrict__ Wdst, float* __restrict__ bdst,
    int rows_per_layer)
{
    const int gw = (blockIdx.x * 256 + threadIdx.x) >> 6;
    const int lane = threadIdx.x & 63;
    const int l = gw / rows_per_layer;
    const float* src = Wsrc + (size_t)gw * D_SZ;
    const float* wv = lnw + l * D_SZ;
    const float* bv = lnb + l * D_SZ;
    unsigned short* dst = Wdst + (size_t)gw * D_SZ;
    float acc = 0.f;
#pragma unroll
    for (int j = 0; j < 3; ++j) {
        int k = lane * 4 + j * 256;
        float4 s = *(const float4*)(src + k);
        float4 w = *(const float4*)(wv + k);
        float4 bb = *(const float4*)(bv + k);
        acc += bb.x * s.x + bb.y * s.y + bb.z * s.z + bb.w * s.w;
        U4 o;
        o.h[0] = __float22bfloat162_rn(float2{s.x * w.x, s.y * w.y});
        o.h[1] = __float22bfloat162_rn(float2{s.z * w.z, s.w * w.w});
        *(ushort4*)(dst + k) = o.u;
    }
#pragma unroll
    for (int off = 32; off; off >>= 1) acc += __shfl_xor(acc, off);
    if (lane == 0) bdst[gw] = bsrc[gw] + acc;
}

// Plain f32 -> bf16 cast, 8 elems/thread
__global__ __launch_bounds__(256) void conv_cast_kernel(
    const float* __restrict__ src, unsigned short* __restrict__ dst, int n8)
{
    int i = blockIdx.x * 256 + threadIdx.x;
    if (i >= n8) return;
    const float* p = src + (size_t)i * 8;
    float4 v0 = *(const float4*)p;
    float4 v1 = *(const float4*)(p + 4);
    B8 r;
    r.h[0] = __float22bfloat162_rn(float2{v0.x, v0.y});
    r.h[1] = __float22bfloat162_rn(float2{v0.z, v0.w});
    r.h[2] = __float22bfloat162_rn(float2{v1.x, v1.y});
    r.h[3] = __float22bfloat162_rn(float2{v1.z, v1.w});
    *(bf16x8*)(dst + (size_t)i * 8) = r.v;
}

// ---------------------------------------------------------------------------
// Embedding gather + rotary
// ---------------------------------------------------------------------------
__global__ __launch_bounds__(256) void embed_rot_kernel(
    const int* __restrict__ ids, const float* __restrict__ emb,
    float* __restrict__ x)
{
    const int tok = blockIdx.x;
    const int s = tok & (S_SZ - 1);
    const int id = ids[tok];
    const float* e = emb + (size_t)id * D_SZ;
    float* xo = x + (size_t)tok * D_SZ;
    const int t = threadIdx.x;

    if (t < 192) {
        float x0 = e[2 * t], x1 = e[2 * t + 1];
        float freq = powf(10000.f, -((float)(2 * t)) / 384.f);
        float ang = (float)s * freq;
        float sn, cs;
        sincosf(ang, &sn, &cs);
        xo[2 * t]     = x0 * cs - x1 * sn;
        xo[2 * t + 1] = x0 * sn + x1 * cs;
    }
    for (int ch = 384 + t; ch < D_SZ; ch += 256) xo[ch] = e[ch];
}

// ---------------------------------------------------------------------------
// MFMA bf16 GEMM.
//  AM: 0 = f32 A (cvt in staging); 1 = f32 A + fused LayerNorm (BM must be 64);
//      2 = bf16 A (direct copy staging)
//  CM: 0 = f32 C (+optional Res);
//      1 = qkv split epilogue -> bf16 Q(scaled)/K [bh][s][64], V^T [bh][64][s];
//      2 = exact GELU -> bf16 C
//  WB16: W already bf16.  XSWZ: XCD-chunked block swizzle (m-fastest inside).
// ---------------------------------------------------------------------------
template<int BM, int BN, int AM, int CM, bool WB16, bool XSWZ>
__global__ __launch_bounds__(256) void mfma_gemm(
    const void* __restrict__ Av, const void* __restrict__ Wv,
    const float* __restrict__ bias, const float* __restrict__ Res,
    float* __restrict__ C,
    unsigned short* __restrict__ qp, unsigned short* __restrict__ kp,
    unsigned short* __restrict__ vp,
    int M, int N, int K)
{
    constexpr int LDST = 48;            // bf16 per LDS row (32 + 16 pad): 4-way banks
    constexpr int MR = BM / 32;
    constexpr int NR = BN / 32;
    constexpr int ACH = BM * 4 / 256;
    constexpr int BCH = BN * 4 / 256;

    __shared__ __align__(16) unsigned short As[2][BM * LDST];
    __shared__ __align__(16) unsigned short Bs[2][BN * LDST];
    __shared__ float smean[AM == 1 ? BM : 1];
    __shared__ float srstd[AM == 1 ? BM : 1];

    const int tid = threadIdx.x;
    const int lane = tid & 63;
    const int wave = tid >> 6;
    const int wrow0 = (wave >> 1) * (BM / 2);
    const int wcol0 = (wave & 1) * (BN / 2);
    const int kgrp = lane >> 4;
    const int rc = lane & 15;

    int m0, n0;
    if constexpr (XSWZ) {
        int nwg = gridDim.x * gridDim.y;
        int id = blockIdx.y * gridDim.x + blockIdx.x;
        int cpx = nwg >> 3;
        int swz = (id & 7) * cpx + (id >> 3);
        m0 = (swz % gridDim.x) * BM;
        n0 = (swz / gridDim.x) * BN;
    } else {
        m0 = blockIdx.x * BM;
        n0 = blockIdx.y * BN;
    }

    if constexpr (AM == 1) {
        const float* A = (const float*)Av;
        const int row = tid >> 2, q = tid & 3;
        const float* xr = A + (size_t)(m0 + row) * K + q * (K >> 2);
        float sum = 0.f, ss = 0.f;
        for (int j = 0; j < (K >> 4); ++j) {
            float4 v = *(const float4*)(xr + j * 4);
            sum += v.x + v.y + v.z + v.w;
            ss += v.x * v.x + v.y * v.y + v.z * v.z + v.w * v.w;
        }
        sum += __shfl_xor(sum, 1); sum += __shfl_xor(sum, 2);
        ss  += __shfl_xor(ss, 1);  ss  += __shfl_xor(ss, 2);
        float mean = sum * (1.f / (float)K);
        float var = ss * (1.f / (float)K) - mean * mean;
        if (q == 0) { smean[row] = mean; srstd[row] = rsqrtf(var + 1e-5f); }
        __syncthreads();
    }

    f32x4 acc[MR][NR];
#pragma unroll
    for (int i = 0; i < MR; ++i)
#pragma unroll
        for (int j = 0; j < NR; ++j) acc[i][j] = (f32x4){0.f, 0.f, 0.f, 0.f};

    float areg[AM != 2 ? ACH : 1][8];
    bf16x8 areg16[AM == 2 ? ACH : 1];
    float bregf[WB16 ? 1 : BCH][WB16 ? 1 : 8];
    bf16x8 breg16[WB16 ? BCH : 1];

    auto stage_load = [&](int k0) {
#pragma unroll
        for (int i = 0; i < ACH; ++i) {
            int c = tid + i * 256;
            int row = c >> 2, ks = c & 3;
            if constexpr (AM == 2) {
                const unsigned short* A16 = (const unsigned short*)Av;
                areg16[i] = *(const bf16x8*)(A16 + (size_t)(m0 + row) * K + k0 + ks * 8);
            } else {
                const float* A = (const float*)Av;
                const float* p = A + (size_t)(m0 + row) * K + k0 + ks * 8;
                float4 v0 = *(const float4*)p;
                float4 v1 = *(const float4*)(p + 4);
                areg[i][0] = v0.x; areg[i][1] = v0.y; areg[i][2] = v0.z; areg[i][3] = v0.w;
                areg[i][4] = v1.x; areg[i][5] = v1.y; areg[i][6] = v1.z; areg[i][7] = v1.w;
            }
        }
#pragma unroll
        for (int i = 0; i < BCH; ++i) {
            int c = tid + i * 256;
            int row = c >> 2, ks = c & 3;
            if constexpr (WB16) {
                const unsigned short* W16 = (const unsigned short*)Wv;
                breg16[i] = *(const bf16x8*)(W16 + (size_t)(n0 + row) * K + k0 + ks * 8);
            } else {
                const float* Wf = (const float*)Wv;
                const float* p = Wf + (size_t)(n0 + row) * K + k0 + ks * 8;
                float4 v0 = *(const float4*)p;
                float4 v1 = *(const float4*)(p + 4);
                bregf[i][0] = v0.x; bregf[i][1] = v0.y; bregf[i][2] = v0.z; bregf[i][3] = v0.w;
                bregf[i][4] = v1.x; bregf[i][5] = v1.y; bregf[i][6] = v1.z; bregf[i][7] = v1.w;
            }
        }
    };
    auto stage_write = [&](int buf) {
#pragma unroll
        for (int i = 0; i < ACH; ++i) {
            int c = tid + i * 256;
            int row = c >> 2, ks = c & 3;
            if constexpr (AM == 2) {
                *(bf16x8*)&As[buf][row * LDST + ks * 8] = areg16[i];
            } else {
                float sc = 1.f, sh = 0.f;
                if constexpr (AM == 1) { sc = srstd[row]; sh = -smean[row] * sc; }
                B8 r;
                r.h[0] = __float22bfloat162_rn(float2{fmaf(areg[i][0], sc, sh), fmaf(areg[i][1], sc, sh)});
                r.h[1] = __float22bfloat162_rn(float2{fmaf(areg[i][2], sc, sh), fmaf(areg[i][3], sc, sh)});
                r.h[2] = __float22bfloat162_rn(float2{fmaf(areg[i][4], sc, sh), fmaf(areg[i][5], sc, sh)});
                r.h[3] = __float22bfloat162_rn(float2{fmaf(areg[i][6], sc, sh), fmaf(areg[i][7], sc, sh)});
                *(bf16x8*)&As[buf][row * LDST + ks * 8] = r.v;
            }
        }
#pragma unroll
        for (int i = 0; i < BCH; ++i) {
            int c = tid + i * 256;
            int row = c >> 2, ks = c & 3;
            if constexpr (WB16) {
                *(bf16x8*)&Bs[buf][row * LDST + ks * 8] = breg16[i];
            } else {
                B8 r;
                r.h[0] = __float22bfloat162_rn(float2{bregf[i][0], bregf[i][1]});
                r.h[1] = __float22bfloat162_rn(float2{bregf[i][2], bregf[i][3]});
                r.h[2] = __float22bfloat162_rn(float2{bregf[i][4], bregf[i][5]});
                r.h[3] = __float22bfloat162_rn(float2{bregf[i][6], bregf[i][7]});
                *(bf16x8*)&Bs[buf][row * LDST + ks * 8] = r.v;
            }
        }
    };

    stage_load(0);
    stage_write(0);
    __syncthreads();

    const int nk = K >> 5;
    int cur = 0;
    for (int s = 0; s < nk; ++s) {
        const bool more = (s + 1 < nk);
        if (more) stage_load((s + 1) << 5);

        bf16x8 af[MR], bf[NR];
#pragma unroll
        for (int mi = 0; mi < MR; ++mi)
            af[mi] = *(const bf16x8*)&As[cur][(wrow0 + mi * 16 + rc) * LDST + kgrp * 8];
#pragma unroll
        for (int ni = 0; ni < NR; ++ni)
            bf[ni] = *(const bf16x8*)&Bs[cur][(wcol0 + ni * 16 + rc) * LDST + kgrp * 8];
#pragma unroll
        for (int mi = 0; mi < MR; ++mi)
#pragma unroll
            for (int ni = 0; ni < NR; ++ni)
                acc[mi][ni] = __builtin_amdgcn_mfma_f32_16x16x32_bf16(
                    af[mi], bf[ni], acc[mi][ni], 0, 0, 0);

        if (more) stage_write(cur ^ 1);
        __syncthreads();
        cur ^= 1;
    }

    // ---- epilogue ----
#pragma unroll
    for (int mi = 0; mi < MR; ++mi) {
#pragma unroll
        for (int ni = 0; ni < NR; ++ni) {
            const int col = n0 + wcol0 + ni * 16 + rc;
            const int rbase = m0 + wrow0 + mi * 16 + kgrp * 4;
            float bv = bias ? bias[col] : 0.f;
            if constexpr (CM == 1) {
                const int region = col / 768;
                const int c768 = col - region * 768;
                const int hh = c768 >> 6, d = c768 & 63;
                const int bb = rbase >> 10, s0 = rbase & 1023;
                const int bh = bb * H_SZ + hh;
                if (region == 0) {
#pragma unroll
                    for (int i = 0; i < 4; ++i)
                        qp[((size_t)(bh << 10) + s0 + i) * 64 + d]
                            = f2bf((acc[mi][ni][i] + bv) * 0.125f);
                } else if (region == 1) {
#pragma unroll
                    for (int i = 0; i < 4; ++i)
                        kp[((size_t)(bh << 10) + s0 + i) * 64 + d]
                            = f2bf(acc[mi][ni][i] + bv);
                } else {
                    U4E t4;
#pragma unroll
                    for (int i = 0; i < 4; ++i) t4.e[i] = f2bf(acc[mi][ni][i] + bv);
                    *(ushort4*)&vp[(((size_t)bh * 64 + d) << 10) + s0] = t4.u;
                }
            } else if constexpr (CM == 2) {
                unsigned short* C16 = (unsigned short*)C;
#pragma unroll
                for (int i = 0; i < 4; ++i) {
                    float v = acc[mi][ni][i] + bv;
                    v = 0.5f * v * (1.f + erff(v * 0.70710678118654752f));
                    C16[(size_t)(rbase + i) * N + col] = f2bf(v);
                }
            } else {
                size_t base = (size_t)rbase * N + col;
#pragma unroll
                for (int i = 0; i < 4; ++i) {
                    float v = acc[mi][ni][i] + bv;
                    size_t idx = base + (size_t)i * N;
                    if (Res) v += Res[idx];
                    C[idx] = v;
                }
            }
        }
    }
}

// ---------------------------------------------------------------------------
// Barrier-free MFMA attention: one 64-thread block (one wave) per causal
// q-block of 16 rows. Q/K bf16 [bh][s][64] (Q pre-scaled), V^T bf16
// [bh][64][s]; MFMA frags load 16B/lane direct from global (L2-resident).
// P round-trips through wave-local LDS only. Heavy q-blocks dispatch first.
// ---------------------------------------------------------------------------
__global__ __launch_bounds__(64) void attn2_kernel(
    const unsigned short* __restrict__ Q16, const unsigned short* __restrict__ K16,
    const unsigned short* __restrict__ VT16, unsigned short* __restrict__ ao16)
{
    const int bid = blockIdx.x;
    const int qb = 63 - bid / 24;          // heavy first
    const int bh = bid % 24;
    const int b = bh / H_SZ, h = bh % H_SZ;
    const int lane = threadIdx.x;
    const int g = lane >> 4, r = lane & 15;

    constexpr int KS = 72;
    __shared__ __align__(16) unsigned short Pl[16 * KS];

    const unsigned short* Qb = Q16 + ((size_t)bh << 10) * 64;
    const unsigned short* Kb = K16 + ((size_t)bh << 10) * 64;
    const unsigned short* Vb = VT16 + ((size_t)bh << 6) * 1024;

    bf16x8 qf[2];
    qf[0] = *(const bf16x8*)&Qb[(qb * 16 + r) * 64 + 8 * g];
    qf[1] = *(const bf16x8*)&Qb[(qb * 16 + r) * 64 + 32 + 8 * g];

    float m_r = -1e30f, l_r = 0.f;
    f32x4 o[4];
#pragma unroll
    for (int ni = 0; ni < 4; ++ni) o[ni] = (f32x4){0.f, 0.f, 0.f, 0.f};

    const int nchunk = (qb >> 2) + 1;
    for (int c = 0; c < nchunk; ++c) {
        const int mi_hi = (c == nchunk - 1) ? (qb & 3) : 3;

        // ---- S^T = K . Q^T ----
        f32x4 s[4];
#pragma unroll
        for (int mi = 0; mi < 4; ++mi) s[mi] = (f32x4){0.f, 0.f, 0.f, 0.f};
#pragma unroll
        for (int mi = 0; mi < 4; ++mi) {
            if (mi <= mi_hi) {
#pragma unroll
                for (int ks = 0; ks < 2; ++ks) {
                    bf16x8 af = *(const bf16x8*)&Kb[(c * 64 + 16 * mi + r) * 64 + 32 * ks + 8 * g];
                    s[mi] = __builtin_amdgcn_mfma_f32_16x16x32_bf16(af, qf[ks], s[mi], 0, 0, 0);
                }
            }
        }

        // ---- online softmax (q-row = r; reduce over g groups) ----
        float mx = -1e30f;
#pragma unroll
        for (int mi = 0; mi < 4; ++mi) {
            if (mi <= mi_hi) {
#pragma unroll
                for (int i = 0; i < 4; ++i) mx = fmaxf(mx, s[mi][i]);
            }
        }
        mx = fmaxf(mx, __shfl_xor(mx, 16));
        mx = fmaxf(mx, __shfl_xor(mx, 32));
        float m_new = fmaxf(m_r, mx);
        float corr = __expf(m_r - m_new);

        float p[4][4];
        float psum = 0.f;
#pragma unroll
        for (int mi = 0; mi < 4; ++mi) {
#pragma unroll
            for (int i = 0; i < 4; ++i) {
                float pv = (mi <= mi_hi) ? __expf(s[mi][i] - m_new) : 0.f;
                p[mi][i] = pv;
                psum += pv;
            }
        }
        psum += __shfl_xor(psum, 16);
        psum += __shfl_xor(psum, 32);
        l_r = l_r * corr + psum;
        m_r = m_new;

        // ---- P -> bf16 -> wave-local LDS ----
#pragma unroll
        for (int mi = 0; mi < 4; ++mi) {
            B4 t;
            t.h[0] = __float22bfloat162_rn(float2{p[mi][0], p[mi][1]});
            t.h[1] = __float22bfloat162_rn(float2{p[mi][2], p[mi][3]});
            *(bf16x4*)&Pl[r * KS + 16 * mi + 4 * g] = t.v;
        }

        // ---- rescale O ----
        float co[4];
#pragma unroll
        for (int i = 0; i < 4; ++i) co[i] = __shfl(corr, 4 * g + i);
#pragma unroll
        for (int ni = 0; ni < 4; ++ni)
#pragma unroll
            for (int i = 0; i < 4; ++i) o[ni][i] *= co[i];

        // ---- PV ----
#pragma unroll
        for (int ks = 0; ks < 2; ++ks) {
            if (c < nchunk - 1 || 2 * ks <= mi_hi) {
                bf16x8 pf = *(const bf16x8*)&Pl[r * KS + 32 * ks + 8 * g];
#pragma unroll
                for (int ni = 0; ni < 4; ++ni) {
                    bf16x8 vf = *(const bf16x8*)&Vb[(size_t)(r + 16 * ni) * 1024 + c * 64 + 32 * ks + 8 * g];
                    o[ni] = __builtin_amdgcn_mfma_f32_16x16x32_bf16(pf, vf, o[ni], 0, 0, 0);
                }
            }
        }
    }

    // ---- finalize ----
    float inv[4];
#pragma unroll
    for (int i = 0; i < 4; ++i) inv[i] = 1.f / __shfl(l_r, 4 * g + i);
#pragma unroll
    for (int ni = 0; ni < 4; ++ni) {
#pragma unroll
        for (int i = 0; i < 4; ++i) {
            ao16[(size_t)(b * S_SZ + qb * 16 + 4 * g + i) * D_SZ + h * HD_SZ + r + 16 * ni]
                = f2bf(o[ni][i] * inv[i]);
        }
    }
}

// ---------------------------------------------------------------------------
// Single-pass online-softmax CE per row
// ---------------------------------------------------------------------------
__global__ __launch_bounds__(256) void ce2_kernel(
    const float* __restrict__ logits, const int* __restrict__ tgt,
    const int* __restrict__ inp, const float* __restrict__ noise,
    float* __restrict__ ce_row, float* __restrict__ msk_row)
{
    const int row = blockIdx.x;
    const int t = threadIdx.x;
    const float* lr = logits + (size_t)row * V_SZ;
    const float4* lr4 = (const float4*)lr;

    float m = -1e30f, s = 0.f;
    for (int i = t; i < V_SZ / 4; i += 256) {
        float4 v = lr4[i];
        float mx4 = fmaxf(fmaxf(v.x, v.y), fmaxf(v.z, v.w));
        if (mx4 > m) { s *= __expf(m - mx4); m = mx4; }
        s += __expf(v.x - m) + __expf(v.y - m) + __expf(v.z - m) + __expf(v.w - m);
    }

    __shared__ float sm[256], ss[256];
    sm[t] = m; ss[t] = s;
    __syncthreads();
    for (int off = 128; off; off >>= 1) {
        if (t < off) {
            float m2 = fmaxf(sm[t], sm[t + off]);
            ss[t] = ss[t] * __expf(sm[t] - m2) + ss[t + off] * __expf(sm[t + off] - m2);
            sm[t] = m2;
        }
        __syncthreads();
    }
    if (t == 0) {
        float M = sm[0], S = ss[0];
        int tg = tgt[row];
        float ce = -(lr[tg] - M - logf(S));
        int ism = (inp[row] == MASK_ID) ? 1 : 0;
        int b = row / S_SZ;
        ce_row[row] = ism ? (ce / noise[b]) : 0.f;
        msk_row[row] = ism ? 1.f : 0.f;
    }
}

__global__ __launch_bounds__(256) void loss_reduce_kernel(
    const float* __restrict__ ce_row, const float* __restrict__ msk_row,
    float* __restrict__ out0)
{
    const int t = threadIdx.x;
    __shared__ float r1[256], r2[256];
    float s = 0.f, c = 0.f;
    for (int i = t; i < NTOK; i += 256) { s += ce_row[i]; c += msk_row[i]; }
    r1[t] = s; r2[t] = c;
    __syncthreads();
    for (int off = 128; off; off >>= 1) {
        if (t < off) { r1[t] += r1[t + off]; r2[t] += r2[t + off]; }
        __syncthreads();
    }
    if (t == 0) out0[0] = r1[0] / (r2[0] + 1e-8f);
}

// ---------------------------------------------------------------------------
// Host launch
// ---------------------------------------------------------------------------
extern "C" void kernel_launch(void* const* d_in, const int* in_sizes, int n_in,
                              void* d_out, int out_size, void* d_ws, size_t ws_size,
                              hipStream_t stream)
{
    const int*   input_ids  = (const int*)d_in[0];
    const int*   target_ids = (const int*)d_in[1];
    const float* noise      = (const float*)d_in[2];
    const float* emb        = (const float*)d_in[3];
    const float* in_w       = (const float*)d_in[4];
    const float* in_b       = (const float*)d_in[5];
    const float* aow        = (const float*)d_in[6];
    const float* aob        = (const float*)d_in[7];
    const float* ln1w       = (const float*)d_in[8];
    const float* ln1b       = (const float*)d_in[9];
    const float* ln2w       = (const float*)d_in[10];
    const float* ln2b       = (const float*)d_in[11];
    const float* w1         = (const float*)d_in[12];
    const float* b1         = (const float*)d_in[13];
    const float* w2         = (const float*)d_in[14];
    const float* b2         = (const float*)d_in[15];
    const float* projw      = (const float*)d_in[16];
    const float* projb      = (const float*)d_in[17];

    float* out    = (float*)d_out;
    float* logits = out + 1;

    // --- scratch inside d_out (dead before the logits GEMM overwrites) ---
    float* base = out + 4;
    unsigned short* wq16 = (unsigned short*)(base);               // 12x2304x768
    unsigned short* wa16 = (unsigned short*)(base + 10616832);    // 12x768x768
    unsigned short* w116 = (unsigned short*)(base + 14155776);    // 12x3072x768
    unsigned short* w216 = (unsigned short*)(base + 28311552);    // 12x768x3072
    float* qkvb2 = base + 42467328;                               // 12x2304
    float* b1b2  = qkvb2 + 27648;                                 // 12x3072
    unsigned short* Q16  = (unsigned short*)(base + 42531840);    // 24x1024x64
    unsigned short* K16  = (unsigned short*)(base + 43318272);
    unsigned short* VT16 = (unsigned short*)(base + 44104704);    // 24x64x1024
    unsigned short* ao16 = (unsigned short*)(base + 44891136);    // 2048x768
    unsigned short* mid16= (unsigned short*)(base + 45677568);    // 2048x3072
    // end: 4 + 48,823,296 floats < 65,536,001 ✓

    // --- d_ws: x f32 + CE rows + optional xb16 + optional projw16 ---
    float* x       = (float*)d_ws;                 // [2048][768] f32
    float* ce_row  = x + (size_t)NTOK * D_SZ;
    float* msk_row = ce_row + NTOK;
    unsigned short* xb16 = (unsigned short*)(msk_row + NTOK);
    unsigned short* projw16 = xb16 + (size_t)NTOK * D_SZ;
    const bool fA = ws_size >= 9453568ull;                  // room for xb16
    const bool fB = ws_size >= 58605568ull;                 // + projw16

    // --- one-time weight conversions ---
    conv_fold_kernel<<<6912, 256, 0, stream>>>(in_w, ln1w, ln1b, in_b, wq16, qkvb2, 2304);
    conv_fold_kernel<<<9216, 256, 0, stream>>>(w1, ln2w, ln2b, b1, w116, b1b2, 3072);
    conv_cast_kernel<<<3456, 256, 0, stream>>>(aow, wa16, 884736);
    conv_cast_kernel<<<13824, 256, 0, stream>>>(w2, w216, 3538944);
    if (fB)
        conv_cast_kernel<<<12000, 256, 0, stream>>>(projw, projw16, 3072000);

    embed_rot_kernel<<<NTOK, 256, 0, stream>>>(input_ids, emb, x);

    for (int l = 0; l < L_SZ; ++l) {
        mfma_gemm<64, 128, 1, 1, true, false><<<dim3(32, 18), 256, 0, stream>>>(
            x, wq16 + (size_t)l * 1769472, qkvb2 + l * 2304, nullptr, nullptr,
            Q16, K16, VT16, NTOK, 2304, 768);
        attn2_kernel<<<1536, 64, 0, stream>>>(Q16, K16, VT16, ao16);
        mfma_gemm<64, 64, 2, 0, true, false><<<dim3(32, 12), 256, 0, stream>>>(
            ao16, wa16 + (size_t)l * 589824, aob + l * D_SZ, x, x,
            nullptr, nullptr, nullptr, NTOK, 768, 768);
        mfma_gemm<64, 128, 1, 2, true, false><<<dim3(32, 24), 256, 0, stream>>>(
            x, w116 + (size_t)l * 2359296, b1b2 + l * 3072, nullptr, (float*)mid16,
            nullptr, nullptr, nullptr, NTOK, 3072, 768);
        mfma_gemm<64, 64, 2, 0, true, false><<<dim3(32, 12), 256, 0, stream>>>(
            mid16, w216 + (size_t)l * 2359296, b2 + l * D_SZ, x, x,
            nullptr, nullptr, nullptr, NTOK, 768, 3072);
    }

    if (fA)
        conv_cast_kernel<<<768, 256, 0, stream>>>(x, xb16, 196608);

    if (fB) {
        mfma_gemm<128, 128, 2, 0, true, true><<<dim3(16, 250), 256, 0, stream>>>(
            xb16, projw16, projb, nullptr, logits,
            nullptr, nullptr, nullptr, NTOK, V_SZ, 768);
    } else if (fA) {
        mfma_gemm<128, 128, 2, 0, false, true><<<dim3(16, 250), 256, 0, stream>>>(
            xb16, projw, projb, nullptr, logits,
            nullptr, nullptr, nullptr, NTOK, V_SZ, 768);
    } else {
        mfma_gemm<128, 128, 0, 0, false, true><<<dim3(16, 250), 256, 0, stream>>>(
            x, projw, projb, nullptr, logits,
            nullptr, nullptr, nullptr, NTOK, V_SZ, 768);
    }

    ce2_kernel<<<NTOK, 256, 0, stream>>>(logits, target_ids, input_ids, noise,
                                         ce_row, msk_row);
    loss_reduce_kernel<<<1, 256, 0, stream>>>(ce_row, msk_row, out);
}

// Round 6
// 2669.382 us; speedup vs baseline: 5.5514x; 1.0364x over previous
//
#include <hip/hip_runtime.h>
#include <hip/hip_bf16.h>
#include <math.h>

// Problem constants
#define V_SZ 32000
#define D_SZ 768
#define H_SZ 12
#define L_SZ 12
#define DF_SZ 3072
#define B_SZ 2
#define S_SZ 1024
#define BS_SZ 16
#define HD_SZ 64
#define MASK_ID 31999
#define NTOK (B_SZ * S_SZ)   // 2048

typedef __attribute__((ext_vector_type(8))) short bf16x8;
typedef __attribute__((ext_vector_type(4))) short bf16x4;
typedef __attribute__((ext_vector_type(4))) float f32x4;

union B8 { bf16x8 v; __hip_bfloat162 h[4]; };
union B4 { bf16x4 v; __hip_bfloat162 h[2]; };
union U4 { ushort4 u; __hip_bfloat162 h[2]; };
union U4E { ushort4 u; unsigned short e[4]; };

__device__ inline unsigned short f2bf(float x) {
    __hip_bfloat16 b = __float2bfloat16(x);
    union { __hip_bfloat16 b; unsigned short u; } c; c.b = b;
    return c.u;
}

// ---------------------------------------------------------------------------
// Weight conversion: fold ln scale into W rows, ln bias into GEMM bias.
// ---------------------------------------------------------------------------
__global__ __launch_bounds__(256) void conv_fold_kernel(
    const float* __restrict__ Wsrc, const float* __restrict__ lnw,
    const float* __restrict__ lnb, const float* __restrict__ bsrc,
    unsigned short* __restrict__ Wdst, float* __restrict__ bdst,
    int rows_per_layer)
{
    const int gw = (blockIdx.x * 256 + threadIdx.x) >> 6;
    const int lane = threadIdx.x & 63;
    const int l = gw / rows_per_layer;
    const float* src = Wsrc + (size_t)gw * D_SZ;
    const float* wv = lnw + l * D_SZ;
    const float* bv = lnb + l * D_SZ;
    unsigned short* dst = Wdst + (size_t)gw * D_SZ;
    float acc = 0.f;
#pragma unroll
    for (int j = 0; j < 3; ++j) {
        int k = lane * 4 + j * 256;
        float4 s = *(const float4*)(src + k);
        float4 w = *(const float4*)(wv + k);
        float4 bb = *(const float4*)(bv + k);
        acc += bb.x * s.x + bb.y * s.y + bb.z * s.z + bb.w * s.w;
        U4 o;
        o.h[0] = __float22bfloat162_rn(float2{s.x * w.x, s.y * w.y});
        o.h[1] = __float22bfloat162_rn(float2{s.z * w.z, s.w * w.w});
        *(ushort4*)(dst + k) = o.u;
    }
#pragma unroll
    for (int off = 32; off; off >>= 1) acc += __shfl_xor(acc, off);
    if (lane == 0) bdst[gw] = bsrc[gw] + acc;
}

// Plain f32 -> bf16 cast, 8 elems/thread
__global__ __launch_bounds__(256) void conv_cast_kernel(
    const float* __restrict__ src, unsigned short* __restrict__ dst, int n8)
{
    int i = blockIdx.x * 256 + threadIdx.x;
    if (i >= n8) return;
    const float* p = src + (size_t)i * 8;
    float4 v0 = *(const float4*)p;
    float4 v1 = *(const float4*)(p + 4);
    B8 r;
    r.h[0] = __float22bfloat162_rn(float2{v0.x, v0.y});
    r.h[1] = __float22bfloat162_rn(float2{v0.z, v0.w});
    r.h[2] = __float22bfloat162_rn(float2{v1.x, v1.y});
    r.h[3] = __float22bfloat162_rn(float2{v1.z, v1.w});
    *(bf16x8*)(dst + (size_t)i * 8) = r.v;
}

// ---------------------------------------------------------------------------
// Embedding gather + rotary
// ---------------------------------------------------------------------------
__global__ __launch_bounds__(256) void embed_rot_kernel(
    const int* __restrict__ ids, const float* __restrict__ emb,
    float* __restrict__ x)
{
    const int tok = blockIdx.x;
    const int s = tok & (S_SZ - 1);
    const int id = ids[tok];
    const float* e = emb + (size_t)id * D_SZ;
    float* xo = x + (size_t)tok * D_SZ;
    const int t = threadIdx.x;

    if (t < 192) {
        float x0 = e[2 * t], x1 = e[2 * t + 1];
        float freq = powf(10000.f, -((float)(2 * t)) / 384.f);
        float ang = (float)s * freq;
        float sn, cs;
        sincosf(ang, &sn, &cs);
        xo[2 * t]     = x0 * cs - x1 * sn;
        xo[2 * t + 1] = x0 * sn + x1 * cs;
    }
    for (int ch = 384 + t; ch < D_SZ; ch += 256) xo[ch] = e[ch];
}

// ---------------------------------------------------------------------------
// MFMA bf16 GEMM with 2-deep global prefetch pipeline.
//  AM: 0 f32 A; 1 f32 A + fused LN (BM==64); 2 bf16 A
//  CM: 0 f32 C (+Res); 1 qkv split epilogue; 2 GELU -> bf16 C
//  WB16: W bf16.  XSWZ: XCD swizzle.  CEP: per-block CE partials (CM==0).
// ---------------------------------------------------------------------------
template<int BM, int BN, int AM, int CM, bool WB16, bool XSWZ, bool CEP>
__global__ __launch_bounds__(256) void mfma_gemm(
    const void* __restrict__ Av, const void* __restrict__ Wv,
    const float* __restrict__ bias, const float* __restrict__ Res,
    float* __restrict__ C,
    unsigned short* __restrict__ qp, unsigned short* __restrict__ kp,
    unsigned short* __restrict__ vp, float2* __restrict__ pm,
    int M, int N, int K)
{
    constexpr int LDST = 48;
    constexpr int MR = BM / 32;
    constexpr int NR = BN / 32;
    constexpr int ACH = BM * 4 / 256;
    constexpr int BCH = BN * 4 / 256;

    __shared__ __align__(16) unsigned short As[2][BM * LDST];
    __shared__ __align__(16) unsigned short Bs[2][BN * LDST];
    __shared__ float smean[AM == 1 ? BM : 1];
    __shared__ float srstd[AM == 1 ? BM : 1];

    const int tid = threadIdx.x;
    const int lane = tid & 63;
    const int wave = tid >> 6;
    const int wrow0 = (wave >> 1) * (BM / 2);
    const int wcol0 = (wave & 1) * (BN / 2);
    const int kgrp = lane >> 4;
    const int rc = lane & 15;

    int m0, n0;
    if constexpr (XSWZ) {
        int nwg = gridDim.x * gridDim.y;
        int id = blockIdx.y * gridDim.x + blockIdx.x;
        int cpx = nwg >> 3;
        int swz = (id & 7) * cpx + (id >> 3);
        m0 = (swz % gridDim.x) * BM;
        n0 = (swz / gridDim.x) * BN;
    } else {
        m0 = blockIdx.x * BM;
        n0 = blockIdx.y * BN;
    }

    if constexpr (AM == 1) {
        const float* A = (const float*)Av;
        const int row = tid >> 2, q = tid & 3;
        const float* xr = A + (size_t)(m0 + row) * K + q * (K >> 2);
        float sum = 0.f, ss = 0.f;
        for (int j = 0; j < (K >> 4); ++j) {
            float4 v = *(const float4*)(xr + j * 4);
            sum += v.x + v.y + v.z + v.w;
            ss += v.x * v.x + v.y * v.y + v.z * v.z + v.w * v.w;
        }
        sum += __shfl_xor(sum, 1); sum += __shfl_xor(sum, 2);
        ss  += __shfl_xor(ss, 1);  ss  += __shfl_xor(ss, 2);
        float mean = sum * (1.f / (float)K);
        float var = ss * (1.f / (float)K) - mean * mean;
        if (q == 0) { smean[row] = mean; srstd[row] = rsqrtf(var + 1e-5f); }
        __syncthreads();
    }

    f32x4 acc[MR][NR];
#pragma unroll
    for (int i = 0; i < MR; ++i)
#pragma unroll
        for (int j = 0; j < NR; ++j) acc[i][j] = (f32x4){0.f, 0.f, 0.f, 0.f};

    // two statically-named register staging sets (2-deep pipeline)
    float areg_0[AM != 2 ? ACH : 1][8], areg_1[AM != 2 ? ACH : 1][8];
    bf16x8 areg16_0[AM == 2 ? ACH : 1], areg16_1[AM == 2 ? ACH : 1];
    float bregf_0[WB16 ? 1 : BCH][8], bregf_1[WB16 ? 1 : BCH][8];
    bf16x8 breg16_0[WB16 ? BCH : 1], breg16_1[WB16 ? BCH : 1];

#define STAGE_LOAD(ST, K0) do {                                              \
    const int k0_ = (K0);                                                    \
    _Pragma("unroll")                                                        \
    for (int i_ = 0; i_ < ACH; ++i_) {                                       \
        int c_ = tid + i_ * 256;                                             \
        int row_ = c_ >> 2, ks_ = c_ & 3;                                    \
        if constexpr (AM == 2) {                                             \
            const unsigned short* A16_ = (const unsigned short*)Av;          \
            areg16_##ST[i_] = *(const bf16x8*)(A16_ + (size_t)(m0 + row_) * K + k0_ + ks_ * 8); \
        } else {                                                             \
            const float* Af_ = (const float*)Av;                             \
            const float* p_ = Af_ + (size_t)(m0 + row_) * K + k0_ + ks_ * 8; \
            float4 v0_ = *(const float4*)p_;                                 \
            float4 v1_ = *(const float4*)(p_ + 4);                           \
            areg_##ST[i_][0] = v0_.x; areg_##ST[i_][1] = v0_.y;              \
            areg_##ST[i_][2] = v0_.z; areg_##ST[i_][3] = v0_.w;              \
            areg_##ST[i_][4] = v1_.x; areg_##ST[i_][5] = v1_.y;              \
            areg_##ST[i_][6] = v1_.z; areg_##ST[i_][7] = v1_.w;              \
        }                                                                    \
    }                                                                        \
    _Pragma("unroll")                                                        \
    for (int i_ = 0; i_ < BCH; ++i_) {                                       \
        int c_ = tid + i_ * 256;                                             \
        int row_ = c_ >> 2, ks_ = c_ & 3;                                    \
        if constexpr (WB16) {                                                \
            const unsigned short* W16_ = (const unsigned short*)Wv;          \
            breg16_##ST[i_] = *(const bf16x8*)(W16_ + (size_t)(n0 + row_) * K + k0_ + ks_ * 8); \
        } else {                                                             \
            const float* Wf_ = (const float*)Wv;                             \
            const float* p_ = Wf_ + (size_t)(n0 + row_) * K + k0_ + ks_ * 8; \
            float4 v0_ = *(const float4*)p_;                                 \
            float4 v1_ = *(const float4*)(p_ + 4);                           \
            bregf_##ST[i_][0] = v0_.x; bregf_##ST[i_][1] = v0_.y;            \
            bregf_##ST[i_][2] = v0_.z; bregf_##ST[i_][3] = v0_.w;            \
            bregf_##ST[i_][4] = v1_.x; bregf_##ST[i_][5] = v1_.y;            \
            bregf_##ST[i_][6] = v1_.z; bregf_##ST[i_][7] = v1_.w;            \
        }                                                                    \
    }                                                                        \
} while (0)

#define STAGE_WRITE(ST, BUF) do {                                            \
    _Pragma("unroll")                                                        \
    for (int i_ = 0; i_ < ACH; ++i_) {                                       \
        int c_ = tid + i_ * 256;                                             \
        int row_ = c_ >> 2, ks_ = c_ & 3;                                    \
        if constexpr (AM == 2) {                                             \
            *(bf16x8*)&As[BUF][row_ * LDST + ks_ * 8] = areg16_##ST[i_];     \
        } else {                                                             \
            float sc_ = 1.f, sh_ = 0.f;                                      \
            if constexpr (AM == 1) { sc_ = srstd[row_]; sh_ = -smean[row_] * sc_; } \
            B8 r_;                                                           \
            r_.h[0] = __float22bfloat162_rn(float2{fmaf(areg_##ST[i_][0], sc_, sh_), fmaf(areg_##ST[i_][1], sc_, sh_)}); \
            r_.h[1] = __float22bfloat162_rn(float2{fmaf(areg_##ST[i_][2], sc_, sh_), fmaf(areg_##ST[i_][3], sc_, sh_)}); \
            r_.h[2] = __float22bfloat162_rn(float2{fmaf(areg_##ST[i_][4], sc_, sh_), fmaf(areg_##ST[i_][5], sc_, sh_)}); \
            r_.h[3] = __float22bfloat162_rn(float2{fmaf(areg_##ST[i_][6], sc_, sh_), fmaf(areg_##ST[i_][7], sc_, sh_)}); \
            *(bf16x8*)&As[BUF][row_ * LDST + ks_ * 8] = r_.v;                \
        }                                                                    \
    }                                                                        \
    _Pragma("unroll")                                                        \
    for (int i_ = 0; i_ < BCH; ++i_) {                                       \
        int c_ = tid + i_ * 256;                                             \
        int row_ = c_ >> 2, ks_ = c_ & 3;                                    \
        if constexpr (WB16) {                                                \
            *(bf16x8*)&Bs[BUF][row_ * LDST + ks_ * 8] = breg16_##ST[i_];     \
        } else {                                                             \
            B8 r_;                                                           \
            r_.h[0] = __float22bfloat162_rn(float2{bregf_##ST[i_][0], bregf_##ST[i_][1]}); \
            r_.h[1] = __float22bfloat162_rn(float2{bregf_##ST[i_][2], bregf_##ST[i_][3]}); \
            r_.h[2] = __float22bfloat162_rn(float2{bregf_##ST[i_][4], bregf_##ST[i_][5]}); \
            r_.h[3] = __float22bfloat162_rn(float2{bregf_##ST[i_][6], bregf_##ST[i_][7]}); \
            *(bf16x8*)&Bs[BUF][row_ * LDST + ks_ * 8] = r_.v;                \
        }                                                                    \
    }                                                                        \
} while (0)

#define COMPUTE(BUF) do {                                                    \
    bf16x8 af_[MR], bf_[NR];                                                 \
    _Pragma("unroll")                                                        \
    for (int mi_ = 0; mi_ < MR; ++mi_)                                       \
        af_[mi_] = *(const bf16x8*)&As[BUF][(wrow0 + mi_ * 16 + rc) * LDST + kgrp * 8]; \
    _Pragma("unroll")                                                        \
    for (int ni_ = 0; ni_ < NR; ++ni_)                                       \
        bf_[ni_] = *(const bf16x8*)&Bs[BUF][(wcol0 + ni_ * 16 + rc) * LDST + kgrp * 8]; \
    _Pragma("unroll")                                                        \
    for (int mi_ = 0; mi_ < MR; ++mi_)                                       \
        _Pragma("unroll")                                                    \
        for (int ni_ = 0; ni_ < NR; ++ni_)                                   \
            acc[mi_][ni_] = __builtin_amdgcn_mfma_f32_16x16x32_bf16(         \
                af_[mi_], bf_[ni_], acc[mi_][ni_], 0, 0, 0);                 \
} while (0)

    const int nk = K >> 5;    // always even here (24, 96)
    // prologue: set0 <- step0; buf0 <- set0; set0 <- step1
    STAGE_LOAD(0, 0);
    STAGE_WRITE(0, 0);
    STAGE_LOAD(0, 32);
    __syncthreads();

    for (int s2 = 0; s2 < nk; s2 += 2) {
        // even step s2: compute buf0; prefetch (s2+2)->set1; write set0->buf1
        if (s2 + 2 < nk) STAGE_LOAD(1, (s2 + 2) << 5);
        COMPUTE(0);
        if (s2 + 1 < nk) STAGE_WRITE(0, 1);
        __syncthreads();
        // odd step s2+1: compute buf1; prefetch (s2+3)->set0; write set1->buf0
        if (s2 + 3 < nk) STAGE_LOAD(0, (s2 + 3) << 5);
        COMPUTE(1);
        if (s2 + 2 < nk) STAGE_WRITE(1, 0);
        __syncthreads();
    }
#undef STAGE_LOAD
#undef STAGE_WRITE
#undef COMPUTE

    // ---- epilogue ----
#pragma unroll
    for (int mi = 0; mi < MR; ++mi) {
#pragma unroll
        for (int ni = 0; ni < NR; ++ni) {
            const int col = n0 + wcol0 + ni * 16 + rc;
            const int rbase = m0 + wrow0 + mi * 16 + kgrp * 4;
            float bv = bias ? bias[col] : 0.f;
            if constexpr (CM == 1) {
                const int region = col / 768;
                const int c768 = col - region * 768;
                const int hh = c768 >> 6, d = c768 & 63;
                const int bb = rbase >> 10, s0 = rbase & 1023;
                const int bh = bb * H_SZ + hh;
                if (region == 0) {
#pragma unroll
                    for (int i = 0; i < 4; ++i)
                        qp[((size_t)(bh << 10) + s0 + i) * 64 + d]
                            = f2bf((acc[mi][ni][i] + bv) * 0.125f);
                } else if (region == 1) {
#pragma unroll
                    for (int i = 0; i < 4; ++i)
                        kp[((size_t)(bh << 10) + s0 + i) * 64 + d]
                            = f2bf(acc[mi][ni][i] + bv);
                } else {
                    U4E t4;
#pragma unroll
                    for (int i = 0; i < 4; ++i) t4.e[i] = f2bf(acc[mi][ni][i] + bv);
                    *(ushort4*)&vp[(((size_t)bh * 64 + d) << 10) + s0] = t4.u;
                }
            } else if constexpr (CM == 2) {
                unsigned short* C16 = (unsigned short*)C;
#pragma unroll
                for (int i = 0; i < 4; ++i) {
                    float v = acc[mi][ni][i] + bv;
                    v = 0.5f * v * (1.f + erff(v * 0.70710678118654752f));
                    C16[(size_t)(rbase + i) * N + col] = f2bf(v);
                }
            } else {
                size_t basei = (size_t)rbase * N + col;
#pragma unroll
                for (int i = 0; i < 4; ++i) {
                    float v = acc[mi][ni][i] + bv;
                    size_t idx = basei + (size_t)i * N;
                    if (Res) v += Res[idx];
                    C[idx] = v;
                }
            }
        }
    }

    // ---- fused CE partials (per-block row max & sumexp over BN cols) ----
    if constexpr (CEP) {
        float2 (*sce)[2] = (float2 (*)[2])As;    // reuse LDS (post-barrier)
        float bvv[NR];
#pragma unroll
        for (int ni = 0; ni < NR; ++ni) bvv[ni] = bias[n0 + wcol0 + ni * 16 + rc];
#pragma unroll
        for (int mi = 0; mi < MR; ++mi) {
#pragma unroll
            for (int i = 0; i < 4; ++i) {
                float vmax = -1e30f;
#pragma unroll
                for (int ni = 0; ni < NR; ++ni)
                    vmax = fmaxf(vmax, acc[mi][ni][i] + bvv[ni]);
                vmax = fmaxf(vmax, __shfl_xor(vmax, 1));
                vmax = fmaxf(vmax, __shfl_xor(vmax, 2));
                vmax = fmaxf(vmax, __shfl_xor(vmax, 4));
                vmax = fmaxf(vmax, __shfl_xor(vmax, 8));
                float ssum = 0.f;
#pragma unroll
                for (int ni = 0; ni < NR; ++ni)
                    ssum += __expf(acc[mi][ni][i] + bvv[ni] - vmax);
                ssum += __shfl_xor(ssum, 1);
                ssum += __shfl_xor(ssum, 2);
                ssum += __shfl_xor(ssum, 4);
                ssum += __shfl_xor(ssum, 8);
                if (rc == 0)
                    sce[wrow0 + mi * 16 + kgrp * 4 + i][wave & 1] = float2{vmax, ssum};
            }
        }
        __syncthreads();
        if (tid < BM) {
            float2 a = sce[tid][0], b2 = sce[tid][1];
            float Mv = fmaxf(a.x, b2.x);
            float Sv = a.y * __expf(a.x - Mv) + b2.y * __expf(b2.x - Mv);
            pm[(size_t)(n0 >> 7) * NTOK + m0 + tid] = float2{Mv, Sv};
        }
    }
}

// ---------------------------------------------------------------------------
// attn3: kv-split-4 MFMA attention. One 256-thread block per (bh, q-block);
// wave w processes chunks c = w, w+4, ... of the same q-block; exact
// log-sum-exp merge of the 4 partials through LDS (one barrier).
// Q/K bf16 [bh][s][64] (Q pre-scaled), V^T bf16 [bh][64][s].
// ---------------------------------------------------------------------------
__global__ __launch_bounds__(256) void attn3_kernel(
    const unsigned short* __restrict__ Q16, const unsigned short* __restrict__ K16,
    const unsigned short* __restrict__ VT16, unsigned short* __restrict__ ao16)
{
    const int bid = blockIdx.x;
    const int qb = 63 - bid / 24;          // heavy first
    const int bh = bid % 24;
    const int b = bh / H_SZ, h = bh % H_SZ;
    const int tid = threadIdx.x;
    const int w = tid >> 6, lane = tid & 63;
    const int g = lane >> 4, r = lane & 15;

    constexpr int KS = 72;
    __shared__ __align__(16) unsigned short Pl[4][16 * KS];
    __shared__ float so[4][16][66];
    __shared__ float2 sml[4][16];

    const unsigned short* Qb = Q16 + ((size_t)bh << 10) * 64;
    const unsigned short* Kb = K16 + ((size_t)bh << 10) * 64;
    const unsigned short* Vb = VT16 + ((size_t)bh << 6) * 1024;

    bf16x8 qf[2];
    qf[0] = *(const bf16x8*)&Qb[(qb * 16 + r) * 64 + 8 * g];
    qf[1] = *(const bf16x8*)&Qb[(qb * 16 + r) * 64 + 32 + 8 * g];

    float m_r = -1e30f, l_r = 0.f;
    f32x4 o[4];
#pragma unroll
    for (int ni = 0; ni < 4; ++ni) o[ni] = (f32x4){0.f, 0.f, 0.f, 0.f};

    const int nch = (qb >> 2) + 1;
    const int qbm = qb & 3;

    for (int c = w; c < nch; c += 4) {
        const bool lastc = (c == nch - 1);
        const int mi_hi = lastc ? qbm : 3;

        // ---- S^T = K . Q^T ----
        f32x4 s[4];
#pragma unroll
        for (int mi = 0; mi < 4; ++mi) s[mi] = (f32x4){0.f, 0.f, 0.f, 0.f};
#pragma unroll
        for (int mi = 0; mi < 4; ++mi) {
            if (mi <= mi_hi) {
#pragma unroll
                for (int ks = 0; ks < 2; ++ks) {
                    bf16x8 af = *(const bf16x8*)&Kb[(c * 64 + 16 * mi + r) * 64 + 32 * ks + 8 * g];
                    s[mi] = __builtin_amdgcn_mfma_f32_16x16x32_bf16(af, qf[ks], s[mi], 0, 0, 0);
                }
            }
        }

        // ---- online softmax (q-row = r; reduce over g groups) ----
        float mx = -1e30f;
#pragma unroll
        for (int mi = 0; mi < 4; ++mi) {
            if (mi <= mi_hi) {
#pragma unroll
                for (int i = 0; i < 4; ++i) mx = fmaxf(mx, s[mi][i]);
            }
        }
        mx = fmaxf(mx, __shfl_xor(mx, 16));
        mx = fmaxf(mx, __shfl_xor(mx, 32));
        float m_new = fmaxf(m_r, mx);
        float corr = __expf(m_r - m_new);

        float p[4][4];
        float psum = 0.f;
#pragma unroll
        for (int mi = 0; mi < 4; ++mi) {
#pragma unroll
            for (int i = 0; i < 4; ++i) {
                float pv = (mi <= mi_hi) ? __expf(s[mi][i] - m_new) : 0.f;
                p[mi][i] = pv;
                psum += pv;
            }
        }
        psum += __shfl_xor(psum, 16);
        psum += __shfl_xor(psum, 32);
        l_r = l_r * corr + psum;
        m_r = m_new;

        // ---- P -> bf16 -> wave-local LDS ----
#pragma unroll
        for (int mi = 0; mi < 4; ++mi) {
            B4 t;
            t.h[0] = __float22bfloat162_rn(float2{p[mi][0], p[mi][1]});
            t.h[1] = __float22bfloat162_rn(float2{p[mi][2], p[mi][3]});
            *(bf16x4*)&Pl[w][r * KS + 16 * mi + 4 * g] = t.v;
        }

        // ---- rescale O ----
        float co[4];
#pragma unroll
        for (int i = 0; i < 4; ++i) co[i] = __shfl(corr, 4 * g + i);
#pragma unroll
        for (int ni = 0; ni < 4; ++ni)
#pragma unroll
            for (int i = 0; i < 4; ++i) o[ni][i] *= co[i];

        // ---- PV ----
#pragma unroll
        for (int ks = 0; ks < 2; ++ks) {
            if (!lastc || 2 * ks <= qbm) {
                bf16x8 pf = *(const bf16x8*)&Pl[w][r * KS + 32 * ks + 8 * g];
#pragma unroll
                for (int ni = 0; ni < 4; ++ni) {
                    bf16x8 vf = *(const bf16x8*)&Vb[(size_t)(r + 16 * ni) * 1024 + c * 64 + 32 * ks + 8 * g];
                    o[ni] = __builtin_amdgcn_mfma_f32_16x16x32_bf16(pf, vf, o[ni], 0, 0, 0);
                }
            }
        }
    }

    // ---- write partials, merge across 4 waves ----
    if (g == 0) sml[w][r] = float2{m_r, l_r};
#pragma unroll
    for (int ni = 0; ni < 4; ++ni)
#pragma unroll
        for (int i = 0; i < 4; ++i)
            so[w][4 * g + i][r + 16 * ni] = o[ni][i];
    __syncthreads();

#pragma unroll
    for (int j = 0; j < 4; ++j) {
        int e = tid + j * 256;
        int row = e >> 6, col = e & 63;
        float2 p0 = sml[0][row], p1 = sml[1][row], p2 = sml[2][row], p3 = sml[3][row];
        float M = fmaxf(fmaxf(p0.x, p1.x), fmaxf(p2.x, p3.x));
        float w0 = __expf(p0.x - M), w1 = __expf(p1.x - M);
        float w2 = __expf(p2.x - M), w3 = __expf(p3.x - M);
        float L = p0.y * w0 + p1.y * w1 + p2.y * w2 + p3.y * w3;
        float ov = so[0][row][col] * w0 + so[1][row][col] * w1
                 + so[2][row][col] * w2 + so[3][row][col] * w3;
        ao16[(size_t)(b * S_SZ + qb * 16 + row) * D_SZ + h * HD_SZ + col]
            = f2bf(ov / L);
    }
}

// ---------------------------------------------------------------------------
// CE: fallback full-row kernel (when ws too small for fused path)
// ---------------------------------------------------------------------------
__global__ __launch_bounds__(256) void ce2_kernel(
    const float* __restrict__ logits, const int* __restrict__ tgt,
    const int* __restrict__ inp, const float* __restrict__ noise,
    float* __restrict__ ce_row, float* __restrict__ msk_row)
{
    const int row = blockIdx.x;
    const int t = threadIdx.x;
    const float* lr = logits + (size_t)row * V_SZ;
    const float4* lr4 = (const float4*)lr;

    float m = -1e30f, s = 0.f;
    for (int i = t; i < V_SZ / 4; i += 256) {
        float4 v = lr4[i];
        float mx4 = fmaxf(fmaxf(v.x, v.y), fmaxf(v.z, v.w));
        if (mx4 > m) { s *= __expf(m - mx4); m = mx4; }
        s += __expf(v.x - m) + __expf(v.y - m) + __expf(v.z - m) + __expf(v.w - m);
    }

    __shared__ float sm[256], ss[256];
    sm[t] = m; ss[t] = s;
    __syncthreads();
    for (int off = 128; off; off >>= 1) {
        if (t < off) {
            float m2 = fmaxf(sm[t], sm[t + off]);
            ss[t] = ss[t] * __expf(sm[t] - m2) + ss[t + off] * __expf(sm[t + off] - m2);
            sm[t] = m2;
        }
        __syncthreads();
    }
    if (t == 0) {
        float M = sm[0], S = ss[0];
        int tg = tgt[row];
        float ce = -(lr[tg] - M - logf(S));
        int ism = (inp[row] == MASK_ID) ? 1 : 0;
        int b = row / S_SZ;
        ce_row[row] = ism ? (ce / noise[b]) : 0.f;
        msk_row[row] = ism ? 1.f : 0.f;
    }
}

// Reduce the 250 per-block partials per row (fused-CE path)
__global__ __launch_bounds__(64) void ce3_kernel(
    const float2* __restrict__ pm, const float* __restrict__ logits,
    const int* __restrict__ tgt, const int* __restrict__ inp,
    const float* __restrict__ noise, float* __restrict__ ce_row,
    float* __restrict__ msk_row)
{
    const int row = blockIdx.x * 64 + threadIdx.x;
    float m = -1e30f, s = 0.f;
    for (int bb = 0; bb < V_SZ / 128; ++bb) {
        float2 p = pm[(size_t)bb * NTOK + row];
        float M2 = fmaxf(m, p.x);
        s = s * __expf(m - M2) + p.y * __expf(p.x - M2);
        m = M2;
    }
    int tg = tgt[row];
    float lv = logits[(size_t)row * V_SZ + tg];
    float ce = -(lv - m - logf(s));
    int ism = (inp[row] == MASK_ID) ? 1 : 0;
    int b = row / S_SZ;
    ce_row[row] = ism ? (ce / noise[b]) : 0.f;
    msk_row[row] = ism ? 1.f : 0.f;
}

__global__ __launch_bounds__(256) void loss_reduce_kernel(
    const float* __restrict__ ce_row, const float* __restrict__ msk_row,
    float* __restrict__ out0)
{
    const int t = threadIdx.x;
    __shared__ float r1[256], r2[256];
    float s = 0.f, c = 0.f;
    for (int i = t; i < NTOK; i += 256) { s += ce_row[i]; c += msk_row[i]; }
    r1[t] = s; r2[t] = c;
    __syncthreads();
    for (int off = 128; off; off >>= 1) {
        if (t < off) { r1[t] += r1[t + off]; r2[t] += r2[t + off]; }
        __syncthreads();
    }
    if (t == 0) out0[0] = r1[0] / (r2[0] + 1e-8f);
}

// ---------------------------------------------------------------------------
// Host launch
// ---------------------------------------------------------------------------
extern "C" void kernel_launch(void* const* d_in, const int* in_sizes, int n_in,
                              void* d_out, int out_size, void* d_ws, size_t ws_size,
                              hipStream_t stream)
{
    const int*   input_ids  = (const int*)d_in[0];
    const int*   target_ids = (const int*)d_in[1];
    const float* noise      = (const float*)d_in[2];
    const float* emb        = (const float*)d_in[3];
    const float* in_w       = (const float*)d_in[4];
    const float* in_b       = (const float*)d_in[5];
    const float* aow        = (const float*)d_in[6];
    const float* aob        = (const float*)d_in[7];
    const float* ln1w       = (const float*)d_in[8];
    const float* ln1b       = (const float*)d_in[9];
    const float* ln2w       = (const float*)d_in[10];
    const float* ln2b       = (const float*)d_in[11];
    const float* w1         = (const float*)d_in[12];
    const float* b1         = (const float*)d_in[13];
    const float* w2         = (const float*)d_in[14];
    const float* b2         = (const float*)d_in[15];
    const float* projw      = (const float*)d_in[16];
    const float* projb      = (const float*)d_in[17];

    float* out    = (float*)d_out;
    float* logits = out + 1;

    // --- scratch inside d_out (dead before the logits GEMM overwrites) ---
    float* base = out + 4;
    unsigned short* wq16 = (unsigned short*)(base);               // 12x2304x768
    unsigned short* wa16 = (unsigned short*)(base + 10616832);    // 12x768x768
    unsigned short* w116 = (unsigned short*)(base + 14155776);    // 12x3072x768
    unsigned short* w216 = (unsigned short*)(base + 28311552);    // 12x768x3072
    float* qkvb2 = base + 42467328;                               // 12x2304
    float* b1b2  = qkvb2 + 27648;                                 // 12x3072
    unsigned short* Q16  = (unsigned short*)(base + 42531840);    // 24x1024x64
    unsigned short* K16  = (unsigned short*)(base + 43318272);
    unsigned short* VT16 = (unsigned short*)(base + 44104704);    // 24x64x1024
    unsigned short* ao16 = (unsigned short*)(base + 44891136);    // 2048x768
    unsigned short* mid16= (unsigned short*)(base + 45677568);    // 2048x3072

    // --- d_ws: x f32 + CE rows + optional xb16 + optional projw16 ---
    float* x       = (float*)d_ws;                 // [2048][768] f32
    float* ce_row  = x + (size_t)NTOK * D_SZ;
    float* msk_row = ce_row + NTOK;
    unsigned short* xb16 = (unsigned short*)(msk_row + NTOK);
    unsigned short* projw16 = xb16 + (size_t)NTOK * D_SZ;
    float2* pm = (float2*)d_ws;                    // CE partials reuse x (dead)
    const bool fA = ws_size >= 9453568ull;                  // room for xb16
    const bool fB = ws_size >= 58605568ull;                 // + projw16

    // --- one-time weight conversions ---
    conv_fold_kernel<<<6912, 256, 0, stream>>>(in_w, ln1w, ln1b, in_b, wq16, qkvb2, 2304);
    conv_fold_kernel<<<9216, 256, 0, stream>>>(w1, ln2w, ln2b, b1, w116, b1b2, 3072);
    conv_cast_kernel<<<3456, 256, 0, stream>>>(aow, wa16, 884736);
    conv_cast_kernel<<<13824, 256, 0, stream>>>(w2, w216, 3538944);
    if (fB)
        conv_cast_kernel<<<12000, 256, 0, stream>>>(projw, projw16, 3072000);

    embed_rot_kernel<<<NTOK, 256, 0, stream>>>(input_ids, emb, x);

    for (int l = 0; l < L_SZ; ++l) {
        mfma_gemm<64, 128, 1, 1, true, false, false><<<dim3(32, 18), 256, 0, stream>>>(
            x, wq16 + (size_t)l * 1769472, qkvb2 + l * 2304, nullptr, nullptr,
            Q16, K16, VT16, nullptr, NTOK, 2304, 768);
        attn3_kernel<<<1536, 256, 0, stream>>>(Q16, K16, VT16, ao16);
        mfma_gemm<64, 64, 2, 0, true, false, false><<<dim3(32, 12), 256, 0, stream>>>(
            ao16, wa16 + (size_t)l * 589824, aob + l * D_SZ, x, x,
            nullptr, nullptr, nullptr, nullptr, NTOK, 768, 768);
        mfma_gemm<64, 128, 1, 2, true, false, false><<<dim3(32, 24), 256, 0, stream>>>(
            x, w116 + (size_t)l * 2359296, b1b2 + l * 3072, nullptr, (float*)mid16,
            nullptr, nullptr, nullptr, nullptr, NTOK, 3072, 768);
        mfma_gemm<64, 64, 2, 0, true, false, false><<<dim3(32, 12), 256, 0, stream>>>(
            mid16, w216 + (size_t)l * 2359296, b2 + l * D_SZ, x, x,
            nullptr, nullptr, nullptr, nullptr, NTOK, 768, 3072);
    }

    if (fA)
        conv_cast_kernel<<<768, 256, 0, stream>>>(x, xb16, 196608);

    if (fB) {
        mfma_gemm<128, 128, 2, 0, true, true, true><<<dim3(16, 250), 256, 0, stream>>>(
            xb16, projw16, projb, nullptr, logits,
            nullptr, nullptr, nullptr, pm, NTOK, V_SZ, 768);
        ce3_kernel<<<32, 64, 0, stream>>>(pm, logits, target_ids, input_ids,
                                          noise, ce_row, msk_row);
    } else if (fA) {
        mfma_gemm<128, 128, 2, 0, false, true, true><<<dim3(16, 250), 256, 0, stream>>>(
            xb16, projw, projb, nullptr, logits,
            nullptr, nullptr, nullptr, pm, NTOK, V_SZ, 768);
        ce3_kernel<<<32, 64, 0, stream>>>(pm, logits, target_ids, input_ids,
                                          noise, ce_row, msk_row);
    } else {
        mfma_gemm<128, 128, 0, 0, false, true, false><<<dim3(16, 250), 256, 0, stream>>>(
            x, projw, projb, nullptr, logits,
            nullptr, nullptr, nullptr, nullptr, NTOK, V_SZ, 768);
        ce2_kernel<<<NTOK, 256, 0, stream>>>(logits, target_ids, input_ids, noise,
                                             ce_row, msk_row);
    }

    loss_reduce_kernel<<<1, 256, 0, stream>>>(ce_row, msk_row, out);
}